// Round 2
// baseline (878.436 us; speedup 1.0000x reference)
//
#include <hip/hip_runtime.h>
#include <cmath>

// ---- problem constants ----
// B=2, d=128, C_bev=256, C_rv=64, Hrv=32, Wrv=1024 (Nq=32768), Hb=Wb=128 (HW=16384)
// heads=8, points=6, hd=16
#define HWB   16384
#define NQTOT 65536      // B * Nq

// ---- workspace layout (float offsets) ----
#define WS_W2T   0UL        // [256][128]  (vp_W @ Wv)^T  c-major
#define WS_BIAS2 32768UL    // [128]       vp_W@bv + vp_b
#define WS_PX    32896UL    // [128][128]  x-major: PX[x][dout]
#define WS_PY    49280UL    // [128][128]
#define WS_WQT   65664UL    // [128][128]  Wq^T
#define WS_SAWT  82048UL    // [128][144]  [so_W ; aw_W]^T
#define WS_OPWT  100480UL   // [128][128]
#define WS_F1T   116864UL
#define WS_F2T   133248UL
#define WS_WOT   149632UL   // [128][64]
#define WS_SAB   157824UL   // [144]
#define WS_Q     157968UL   // [65536][128]   q ; later reused as yf
#define WS_YF    157968UL
#define WS_V     8546576UL  // [2*16384][128]
#define WS_SA    12740880UL // [65536][144]   sa ; later region reused as y1
#define WS_Y1    12740880UL // [65536][128]
#define WS_MS    22178064UL // [65536][128]   msda out ; later FFN hidden t
#define WS_T     22178064UL
// total = 30,566,672 floats = 122.3 MB

#define FMA4(A, S, W) { A.x += (S)*(W).x; A.y += (S)*(W).y; A.z += (S)*(W).z; A.w += (S)*(W).w; }
#define ADD4(A, B4)   { A.x += (B4).x;    A.y += (B4).y;    A.z += (B4).z;    A.w += (B4).w;    }

// ============ prep: fused/transposed weight tables ============
__global__ __launch_bounds__(256) void prep_k(
    const float* __restrict__ vpW, const float* __restrict__ Wv,
    const float* __restrict__ bv,  const float* __restrict__ vpb,
    const float* __restrict__ Wq,  const float* __restrict__ soW,
    const float* __restrict__ awW, const float* __restrict__ opW,
    const float* __restrict__ f1W, const float* __restrict__ f2W,
    const float* __restrict__ Wo,  const float* __restrict__ sob,
    const float* __restrict__ awb, float* __restrict__ ws)
{
    int idx = blockIdx.x * 256 + threadIdx.x;
    const float NEG = -0.14391156831212787f;   // -ln(10000)/64
    if (idx < 32768) {                         // W2T[c][dout] = sum_k vpW[dout,k]*Wv[k,c]
        int c = idx >> 7, dd = idx & 127;
        float s = 0.f;
        for (int k = 0; k < 128; ++k) s += vpW[dd*128 + k] * Wv[k*256 + c];
        ws[WS_W2T + idx] = s;
        return;
    }
    idx -= 32768;
    if (idx < 128) {                           // bias2 = vpW@bv + vpb
        float s = vpb[idx];
        for (int k = 0; k < 128; ++k) s += vpW[idx*128 + k] * bv[k];
        ws[WS_BIAS2 + idx] = s;
        return;
    }
    idx -= 128;
    if (idx < 16384) {                         // PX[x][dout]
        int x = idx >> 7, dd = idx & 127;
        float fx = (float)x, s = 0.f;
        for (int i = 0; i < 32; ++i) {
            float dv = expf((float)(2*i) * NEG);
            float sv, cv; sincosf(fx * dv, &sv, &cv);
            s += vpW[dd*128 + 2*i] * sv + vpW[dd*128 + 2*i + 1] * cv;
        }
        ws[WS_PX + idx] = s;
        return;
    }
    idx -= 16384;
    if (idx < 16384) {                         // PY[y][dout]
        int y = idx >> 7, dd = idx & 127;
        float fy = (float)y, s = 0.f;
        for (int i = 0; i < 32; ++i) {
            float dv = expf((float)(2*i) * NEG);
            float sv, cv; sincosf(fy * dv, &sv, &cv);
            s += vpW[dd*128 + 64 + 2*i] * sv + vpW[dd*128 + 64 + 2*i + 1] * cv;
        }
        ws[WS_PY + idx] = s;
        return;
    }
    idx -= 16384;
    if (idx < 16384) { ws[WS_WQT  + idx] = Wq [(idx & 127)*128 + (idx >> 7)]; return; }
    idx -= 16384;
    if (idx < 18432) {                         // SAWT[c][j]
        int c = idx / 144, j = idx % 144;
        ws[WS_SAWT + idx] = (j < 96) ? soW[j*128 + c] : awW[(j-96)*128 + c];
        return;
    }
    idx -= 18432;
    if (idx < 16384) { ws[WS_OPWT + idx] = opW[(idx & 127)*128 + (idx >> 7)]; return; }
    idx -= 16384;
    if (idx < 16384) { ws[WS_F1T  + idx] = f1W[(idx & 127)*128 + (idx >> 7)]; return; }
    idx -= 16384;
    if (idx < 16384) { ws[WS_F2T  + idx] = f2W[(idx & 127)*128 + (idx >> 7)]; return; }
    idx -= 16384;
    if (idx < 8192)  { ws[WS_WOT  + idx] = Wo [(idx & 63)*128 + (idx >> 6)]; return; }
    idx -= 8192;
    if (idx < 144)   { ws[WS_SAB  + idx] = (idx < 96) ? sob[idx] : awb[idx - 96]; }
}

// ============ value: v = W2T.bev + PX[x] + PY[y] + bias2  (K=256 GEMM tile) ============
__global__ __launch_bounds__(256) void value_k(const float* __restrict__ bev, float* __restrict__ ws)
{
    __shared__ __align__(16) float bt[256 * 32];   // [c][pos]
    int t = threadIdx.x, blk = blockIdx.x;
    int b = blk >> 9;                              // 512 tiles per batch
    int n0 = (blk & 511) << 5;
    const float* src = bev + (size_t)b * 256 * HWB + n0;
#pragma unroll
    for (int i = 0; i < 32; ++i) {
        int flat = i * 256 + t;
        bt[flat] = src[(size_t)(flat >> 5) * HWB + (flat & 31)];
    }
    __syncthreads();
    int p0 = (t >> 5) << 2, d0 = (t & 31) << 2;
    float4 a0 = {0,0,0,0}, a1 = a0, a2 = a0, a3 = a0;
    const float* WT = ws + WS_W2T;
    for (int c = 0; c < 256; ++c) {
        float4 xv = *(const float4*)&bt[c*32 + p0];
        float4 wv = *(const float4*)&WT[c*128 + d0];
        FMA4(a0, xv.x, wv); FMA4(a1, xv.y, wv); FMA4(a2, xv.z, wv); FMA4(a3, xv.w, wv);
    }
    const float* PX = ws + WS_PX; const float* PY = ws + WS_PY;
    float4 b2 = *(const float4*)&ws[WS_BIAS2 + d0];
    float* vout = ws + WS_V;
#define VSTORE(ACC, PI) { \
        int n = n0 + p0 + (PI); int x = n & 127, y = n >> 7; \
        float4 px = *(const float4*)&PX[x*128 + d0]; \
        float4 py = *(const float4*)&PY[y*128 + d0]; \
        ADD4(ACC, px); ADD4(ACC, py); ADD4(ACC, b2); \
        *(float4*)&vout[((size_t)b*HWB + n)*128 + d0] = ACC; }
    VSTORE(a0, 0) VSTORE(a1, 1) VSTORE(a2, 2) VSTORE(a3, 3)
#undef VSTORE
}

// ============ q = WqT.rv + bq  (K=128 GEMM tile, transposed input) ============
__global__ __launch_bounds__(256) void q_k(const float* __restrict__ rv, const float* __restrict__ bq,
                                           float* __restrict__ ws)
{
    __shared__ __align__(16) float bt[128 * 32];
    int t = threadIdx.x, blk = blockIdx.x;
    int b = blk >> 10;                             // 1024 tiles per batch
    int n0 = (blk & 1023) << 5;
    const float* src = rv + (size_t)b * 128 * 32768 + n0;
#pragma unroll
    for (int i = 0; i < 16; ++i) {
        int flat = i * 256 + t;
        bt[flat] = src[(size_t)(flat >> 5) * 32768 + (flat & 31)];
    }
    __syncthreads();
    int p0 = (t >> 5) << 2, d0 = (t & 31) << 2;
    float4 a0 = {0,0,0,0}, a1 = a0, a2 = a0, a3 = a0;
    const float* WT = ws + WS_WQT;
    for (int c = 0; c < 128; ++c) {
        float4 xv = *(const float4*)&bt[c*32 + p0];
        float4 wv = *(const float4*)&WT[c*128 + d0];
        FMA4(a0, xv.x, wv); FMA4(a1, xv.y, wv); FMA4(a2, xv.z, wv); FMA4(a3, xv.w, wv);
    }
    float4 bb = *(const float4*)&bq[d0];
    float* qout = ws + WS_Q + ((size_t)b * 32768 + n0) * 128;
#define QSTORE(ACC, PI) { ADD4(ACC, bb); *(float4*)&qout[(size_t)(p0 + (PI))*128 + d0] = ACC; }
    QSTORE(a0, 0) QSTORE(a1, 1) QSTORE(a2, 2) QSTORE(a3, 3)
#undef QSTORE
}

// ============ sa = q @ SAWT + sab   [65536][144] ============
__global__ __launch_bounds__(256) void sa_k(float* __restrict__ ws)
{
    __shared__ __align__(16) float xt[16 * 132];
    int t = threadIdx.x;
    size_t row0 = (size_t)blockIdx.x * 16;
    const float* src = ws + WS_Q + row0 * 128;
#pragma unroll
    for (int i = 0; i < 2; ++i) {
        int f4 = i * 256 + t; int r = f4 >> 5, c4 = f4 & 31;
        *(float4*)&xt[r*132 + c4*4] = *(const float4*)&src[r*128 + c4*4];
    }
    __syncthreads();
    int r = t >> 4, j0 = t & 15;
    float acc[9] = {0,0,0,0,0,0,0,0,0};
    const float* WT = ws + WS_SAWT;
    for (int c = 0; c < 128; ++c) {
        float xv = xt[r*132 + c];
        const float* wr = WT + c*144 + j0;
#pragma unroll
        for (int k = 0; k < 9; ++k) acc[k] += xv * wr[16*k];
    }
    float* dst = ws + WS_SA + (row0 + r) * 144;
    const float* sab = ws + WS_SAB;
#pragma unroll
    for (int k = 0; k < 9; ++k) dst[j0 + 16*k] = acc[k] + sab[j0 + 16*k];
}

// ============ sampling: softmax over P, bilinear gather, weighted sum ============
__global__ __launch_bounds__(256) void samp_k(const float* __restrict__ ref, float* __restrict__ ws)
{
    int t = threadIdx.x;
    int w = t >> 6, l = t & 63;
    int g = blockIdx.x * 4 + w;                    // query id, < 65536
    int b = g >> 15;
    const float* sa = ws + WS_SA + (size_t)g * 144;
    int hh = l >> 3, s = l & 7;
    // softmax over the 6 points of this head (redundant across the head's 8 lanes)
    float lg[6]; float mx = -1e30f;
#pragma unroll
    for (int p = 0; p < 6; ++p) { lg[p] = sa[96 + hh*6 + p]; mx = fmaxf(mx, lg[p]); }
    float ssum = 0.f;
#pragma unroll
    for (int p = 0; p < 6; ++p) { lg[p] = expf(lg[p] - mx); ssum += lg[p]; }
    float inv = 1.f / ssum;
    float rx = ref[(size_t)g*2], ry = ref[(size_t)g*2 + 1];
    const float* vb = ws + WS_V + ((size_t)b * HWB) * 128 + hh*16 + s*2;
    float a0 = 0.f, a1 = 0.f;
#pragma unroll
    for (int p = 0; p < 6; ++p) {
        float ox = sa[(hh*6 + p)*2], oy = sa[(hh*6 + p)*2 + 1];
        float xx = (rx + ox * 0.0078125f) * 128.f - 0.5f;   // (ref + off/W)*W - 0.5
        float yy = (ry + oy * 0.0078125f) * 128.f - 0.5f;
        float xf = floorf(xx), yf = floorf(yy);
        float lx = xx - xf, ly = yy - yf;
        int ix = (int)xf, iy = (int)yf;
        float c0 = 0.f, c1 = 0.f;
#define CORNER(XI, YI, WW) { int xi = (XI), yi = (YI); \
        if (xi >= 0 && xi < 128 && yi >= 0 && yi < 128) { \
            const float2 gv = *(const float2*)(vb + (size_t)(yi*128 + xi)*128); \
            float wv = (WW); c0 += wv * gv.x; c1 += wv * gv.y; } }
        CORNER(ix,     iy,     (1.f-lx)*(1.f-ly));
        CORNER(ix + 1, iy,     lx*(1.f-ly));
        CORNER(ix,     iy + 1, (1.f-lx)*ly);
        CORNER(ix + 1, iy + 1, lx*ly);
#undef CORNER
        float aw = lg[p] * inv;
        a0 += aw * c0; a1 += aw * c1;
    }
    float2 r2; r2.x = a0; r2.y = a1;
    *(float2*)(ws + WS_MS + (size_t)g*128 + hh*16 + s*2) = r2;
}

// ============ op proj + residual(q) + LN1 -> y1 ============
__global__ __launch_bounds__(256) void opln_k(const float* __restrict__ opb,
    const float* __restrict__ ln1g, const float* __restrict__ ln1b, float* __restrict__ ws)
{
    __shared__ __align__(16) float xt[16 * 132];
    int t = threadIdx.x;
    size_t row0 = (size_t)blockIdx.x * 16;
    const float* src = ws + WS_MS + row0 * 128;
#pragma unroll
    for (int i = 0; i < 2; ++i) {
        int f4 = i * 256 + t; int r = f4 >> 5, c4 = f4 & 31;
        *(float4*)&xt[r*132 + c4*4] = *(const float4*)&src[r*128 + c4*4];
    }
    __syncthreads();
    int r = t >> 4, j0 = (t & 15) << 2;
    const float* WT = ws + WS_OPWT;
    float4 A = {0,0,0,0}, Bv = {0,0,0,0};
    for (int c = 0; c < 128; ++c) {
        float xv = xt[r*132 + c];
        float4 wa = *(const float4*)&WT[c*128 + j0];
        float4 wb = *(const float4*)&WT[c*128 + j0 + 64];
        FMA4(A, xv, wa); FMA4(Bv, xv, wb);
    }
    size_t g = row0 + r;
    const float* qrow = ws + WS_Q + g * 128;
    float4 qa = *(const float4*)&qrow[j0], qb = *(const float4*)&qrow[j0 + 64];
    float4 oa = *(const float4*)&opb[j0], ob = *(const float4*)&opb[j0 + 64];
    ADD4(A, qa); ADD4(A, oa); ADD4(Bv, qb); ADD4(Bv, ob);
    float sm = A.x + A.y + A.z + A.w + Bv.x + Bv.y + Bv.z + Bv.w;
    sm += __shfl_xor(sm, 1); sm += __shfl_xor(sm, 2); sm += __shfl_xor(sm, 4); sm += __shfl_xor(sm, 8);
    float mean = sm * 0.0078125f;
    A.x -= mean; A.y -= mean; A.z -= mean; A.w -= mean;
    Bv.x -= mean; Bv.y -= mean; Bv.z -= mean; Bv.w -= mean;
    float vv = A.x*A.x + A.y*A.y + A.z*A.z + A.w*A.w + Bv.x*Bv.x + Bv.y*Bv.y + Bv.z*Bv.z + Bv.w*Bv.w;
    vv += __shfl_xor(vv, 1); vv += __shfl_xor(vv, 2); vv += __shfl_xor(vv, 4); vv += __shfl_xor(vv, 8);
    float rstd = rsqrtf(vv * 0.0078125f + 1e-5f);
    float4 ga = *(const float4*)&ln1g[j0], gb = *(const float4*)&ln1g[j0 + 64];
    float4 la = *(const float4*)&ln1b[j0], lb = *(const float4*)&ln1b[j0 + 64];
    float4 ra, rb;
    ra.x = A.x*rstd*ga.x + la.x;  ra.y = A.y*rstd*ga.y + la.y;
    ra.z = A.z*rstd*ga.z + la.z;  ra.w = A.w*rstd*ga.w + la.w;
    rb.x = Bv.x*rstd*gb.x + lb.x; rb.y = Bv.y*rstd*gb.y + lb.y;
    rb.z = Bv.z*rstd*gb.z + lb.z; rb.w = Bv.w*rstd*gb.w + lb.w;
    float* dst = ws + WS_Y1 + g * 128;
    *(float4*)&dst[j0] = ra; *(float4*)&dst[j0 + 64] = rb;
}

// ============ FFN hidden: t = gelu(y1 @ f1T + f1b) ============
__global__ __launch_bounds__(256) void f1_k(const float* __restrict__ f1b, float* __restrict__ ws)
{
    __shared__ __align__(16) float xt[16 * 132];
    int t = threadIdx.x;
    size_t row0 = (size_t)blockIdx.x * 16;
    const float* src = ws + WS_Y1 + row0 * 128;
#pragma unroll
    for (int i = 0; i < 2; ++i) {
        int f4 = i * 256 + t; int r = f4 >> 5, c4 = f4 & 31;
        *(float4*)&xt[r*132 + c4*4] = *(const float4*)&src[r*128 + c4*4];
    }
    __syncthreads();
    int r = t >> 4, j0 = (t & 15) << 2;
    const float* WT = ws + WS_F1T;
    float4 A = {0,0,0,0}, Bv = {0,0,0,0};
    for (int c = 0; c < 128; ++c) {
        float xv = xt[r*132 + c];
        float4 wa = *(const float4*)&WT[c*128 + j0];
        float4 wb = *(const float4*)&WT[c*128 + j0 + 64];
        FMA4(A, xv, wa); FMA4(Bv, xv, wb);
    }
    float4 ba = *(const float4*)&f1b[j0], bb = *(const float4*)&f1b[j0 + 64];
    ADD4(A, ba); ADD4(Bv, bb);
#define GELU(X) ((X) = 0.5f*(X)*(1.f + erff((X)*0.70710678118654752f)))
    GELU(A.x); GELU(A.y); GELU(A.z); GELU(A.w);
    GELU(Bv.x); GELU(Bv.y); GELU(Bv.z); GELU(Bv.w);
#undef GELU
    float* dst = ws + WS_T + (row0 + r) * 128;
    *(float4*)&dst[j0] = A; *(float4*)&dst[j0 + 64] = Bv;
}

// ============ z = t @ f2T + f2b + y1 ; LN2 -> yf ============
__global__ __launch_bounds__(256) void f2ln_k(const float* __restrict__ f2b,
    const float* __restrict__ ln2g, const float* __restrict__ ln2b, float* __restrict__ ws)
{
    __shared__ __align__(16) float xt[16 * 132];
    int t = threadIdx.x;
    size_t row0 = (size_t)blockIdx.x * 16;
    const float* src = ws + WS_T + row0 * 128;
#pragma unroll
    for (int i = 0; i < 2; ++i) {
        int f4 = i * 256 + t; int r = f4 >> 5, c4 = f4 & 31;
        *(float4*)&xt[r*132 + c4*4] = *(const float4*)&src[r*128 + c4*4];
    }
    __syncthreads();
    int r = t >> 4, j0 = (t & 15) << 2;
    const float* WT = ws + WS_F2T;
    float4 A = {0,0,0,0}, Bv = {0,0,0,0};
    for (int c = 0; c < 128; ++c) {
        float xv = xt[r*132 + c];
        float4 wa = *(const float4*)&WT[c*128 + j0];
        float4 wb = *(const float4*)&WT[c*128 + j0 + 64];
        FMA4(A, xv, wa); FMA4(Bv, xv, wb);
    }
    size_t g = row0 + r;
    const float* yr = ws + WS_Y1 + g * 128;
    float4 ya = *(const float4*)&yr[j0], yb = *(const float4*)&yr[j0 + 64];
    float4 ba = *(const float4*)&f2b[j0], bb = *(const float4*)&f2b[j0 + 64];
    ADD4(A, ya); ADD4(A, ba); ADD4(Bv, yb); ADD4(Bv, bb);
    float sm = A.x + A.y + A.z + A.w + Bv.x + Bv.y + Bv.z + Bv.w;
    sm += __shfl_xor(sm, 1); sm += __shfl_xor(sm, 2); sm += __shfl_xor(sm, 4); sm += __shfl_xor(sm, 8);
    float mean = sm * 0.0078125f;
    A.x -= mean; A.y -= mean; A.z -= mean; A.w -= mean;
    Bv.x -= mean; Bv.y -= mean; Bv.z -= mean; Bv.w -= mean;
    float vv = A.x*A.x + A.y*A.y + A.z*A.z + A.w*A.w + Bv.x*Bv.x + Bv.y*Bv.y + Bv.z*Bv.z + Bv.w*Bv.w;
    vv += __shfl_xor(vv, 1); vv += __shfl_xor(vv, 2); vv += __shfl_xor(vv, 4); vv += __shfl_xor(vv, 8);
    float rstd = rsqrtf(vv * 0.0078125f + 1e-5f);
    float4 ga = *(const float4*)&ln2g[j0], gb = *(const float4*)&ln2g[j0 + 64];
    float4 la = *(const float4*)&ln2b[j0], lb = *(const float4*)&ln2b[j0 + 64];
    float4 ra, rb;
    ra.x = A.x*rstd*ga.x + la.x;  ra.y = A.y*rstd*ga.y + la.y;
    ra.z = A.z*rstd*ga.z + la.z;  ra.w = A.w*rstd*ga.w + la.w;
    rb.x = Bv.x*rstd*gb.x + lb.x; rb.y = Bv.y*rstd*gb.y + lb.y;
    rb.z = Bv.z*rstd*gb.z + lb.z; rb.w = Bv.w*rstd*gb.w + lb.w;
    float* dst = ws + WS_YF + g * 128;
    *(float4*)&dst[j0] = ra; *(float4*)&dst[j0 + 64] = rb;
}

// ============ out = yf @ WoT + bo  [65536][64] ============
__global__ __launch_bounds__(256) void out_k(const float* __restrict__ bo,
                                             float* __restrict__ out, float* __restrict__ ws)
{
    __shared__ __align__(16) float xt[16 * 132];
    int t = threadIdx.x;
    size_t row0 = (size_t)blockIdx.x * 16;
    const float* src = ws + WS_YF + row0 * 128;
#pragma unroll
    for (int i = 0; i < 2; ++i) {
        int f4 = i * 256 + t; int r = f4 >> 5, c4 = f4 & 31;
        *(float4*)&xt[r*132 + c4*4] = *(const float4*)&src[r*128 + c4*4];
    }
    __syncthreads();
    int r = t >> 4, j0 = (t & 15) << 2;
    const float* WT = ws + WS_WOT;
    float4 A = {0,0,0,0};
    for (int c = 0; c < 128; ++c) {
        float xv = xt[r*132 + c];
        float4 wa = *(const float4*)&WT[c*64 + j0];
        FMA4(A, xv, wa);
    }
    float4 ba = *(const float4*)&bo[j0];
    ADD4(A, ba);
    *(float4*)&out[(row0 + r)*64 + j0] = A;
}

extern "C" void kernel_launch(void* const* d_in, const int* in_sizes, int n_in,
                              void* d_out, int out_size, void* d_ws, size_t ws_size,
                              hipStream_t stream) {
    const float* rv   = (const float*)d_in[0];
    const float* bev  = (const float*)d_in[1];
    const float* ref  = (const float*)d_in[2];
    const float* Wq   = (const float*)d_in[3];
    const float* bq   = (const float*)d_in[4];
    const float* Wv   = (const float*)d_in[5];
    const float* bv   = (const float*)d_in[6];
    const float* soW  = (const float*)d_in[7];
    const float* sob  = (const float*)d_in[8];
    const float* awW  = (const float*)d_in[9];
    const float* awb  = (const float*)d_in[10];
    const float* vpW  = (const float*)d_in[11];
    const float* vpb  = (const float*)d_in[12];
    const float* opW  = (const float*)d_in[13];
    const float* opb  = (const float*)d_in[14];
    const float* ln1g = (const float*)d_in[15];
    const float* ln1b = (const float*)d_in[16];
    const float* f1W  = (const float*)d_in[17];
    const float* f1b  = (const float*)d_in[18];
    const float* f2W  = (const float*)d_in[19];
    const float* f2b  = (const float*)d_in[20];
    const float* ln2g = (const float*)d_in[21];
    const float* ln2b = (const float*)d_in[22];
    const float* Wo   = (const float*)d_in[23];
    const float* bo   = (const float*)d_in[24];
    float* ws  = (float*)d_ws;
    float* out = (float*)d_out;

    prep_k <<<618,   256, 0, stream>>>(vpW, Wv, bv, vpb, Wq, soW, awW, opW, f1W, f2W, Wo, sob, awb, ws);
    value_k<<<1024,  256, 0, stream>>>(bev, ws);
    q_k    <<<2048,  256, 0, stream>>>(rv, bq, ws);
    sa_k   <<<4096,  256, 0, stream>>>(ws);
    samp_k <<<16384, 256, 0, stream>>>(ref, ws);
    opln_k <<<4096,  256, 0, stream>>>(opb, ln1g, ln1b, ws);
    f1_k   <<<4096,  256, 0, stream>>>(f1b, ws);
    f2ln_k <<<4096,  256, 0, stream>>>(f2b, ln2g, ln2b, ws);
    out_k  <<<4096,  256, 0, stream>>>(bo, out, ws);
}

// Round 3
// 774.272 us; speedup vs baseline: 1.1345x; 1.1345x over previous
//
#include <hip/hip_runtime.h>
#include <cmath>

// ---- problem constants ----
// B=2, d=128, C_bev=256, C_rv=64, Hrv=32, Wrv=1024 (Nq=32768), Hb=Wb=128 (HW=16384)
// heads=8, points=6, hd=16
#define HWB   16384
#define NQTOT 65536      // B * Nq

// ---- workspace layout (float offsets) ----
#define WS_W2T   0UL        // [256][128]  (vp_W @ Wv)^T  c-major
#define WS_BIAS2 32768UL    // [128]       vp_W@bv + vp_b
#define WS_PX    32896UL    // [128][128]  x-major: PX[x][dout]
#define WS_PY    49280UL    // [128][128]
#define WS_WQT   65664UL    // [128][128]  Wq^T
#define WS_SAWT  82048UL    // [128][144]  [so_W ; aw_W]^T
#define WS_OPWT  100480UL   // [128][128]
#define WS_F1T   116864UL
#define WS_F2T   133248UL
#define WS_WOT   149632UL   // [128][64]
#define WS_SAB   157824UL   // [144]
#define WS_Q     157968UL   // [65536][128]   q (live until opln residual)
#define WS_V     8546576UL  // [2*16384][128]
#define WS_SA    12740880UL // [65536][144]   sa ; later region reused as y1
#define WS_Y1    12740880UL // [65536][128]
#define WS_MS    22178064UL // [65536][128]   msda out ; later FFN hidden t
#define WS_T     22178064UL
// total = 30,566,672 floats = 122.3 MB

#define FMA4(A, S, W) { A.x += (S)*(W).x; A.y += (S)*(W).y; A.z += (S)*(W).z; A.w += (S)*(W).w; }
#define ADD4(A, B4)   { A.x += (B4).x;    A.y += (B4).y;    A.z += (B4).z;    A.w += (B4).w;    }

// ============ prep: fused/transposed weight tables ============
__global__ __launch_bounds__(256) void prep_k(
    const float* __restrict__ vpW, const float* __restrict__ Wv,
    const float* __restrict__ bv,  const float* __restrict__ vpb,
    const float* __restrict__ Wq,  const float* __restrict__ soW,
    const float* __restrict__ awW, const float* __restrict__ opW,
    const float* __restrict__ f1W, const float* __restrict__ f2W,
    const float* __restrict__ Wo,  const float* __restrict__ sob,
    const float* __restrict__ awb, float* __restrict__ ws)
{
    int idx = blockIdx.x * 256 + threadIdx.x;
    const float NEG = -0.14391156831212787f;   // -ln(10000)/64
    if (idx < 32768) {                         // W2T[c][dout] = sum_k vpW[dout,k]*Wv[k,c]
        int c = idx >> 7, dd = idx & 127;
        float s = 0.f;
        for (int k = 0; k < 128; ++k) s += vpW[dd*128 + k] * Wv[k*256 + c];
        ws[WS_W2T + idx] = s;
        return;
    }
    idx -= 32768;
    if (idx < 128) {                           // bias2 = vpW@bv + vpb
        float s = vpb[idx];
        for (int k = 0; k < 128; ++k) s += vpW[idx*128 + k] * bv[k];
        ws[WS_BIAS2 + idx] = s;
        return;
    }
    idx -= 128;
    if (idx < 16384) {                         // PX[x][dout]
        int x = idx >> 7, dd = idx & 127;
        float fx = (float)x, s = 0.f;
        for (int i = 0; i < 32; ++i) {
            float dv = expf((float)(2*i) * NEG);
            float sv, cv; sincosf(fx * dv, &sv, &cv);
            s += vpW[dd*128 + 2*i] * sv + vpW[dd*128 + 2*i + 1] * cv;
        }
        ws[WS_PX + idx] = s;
        return;
    }
    idx -= 16384;
    if (idx < 16384) {                         // PY[y][dout]
        int y = idx >> 7, dd = idx & 127;
        float fy = (float)y, s = 0.f;
        for (int i = 0; i < 32; ++i) {
            float dv = expf((float)(2*i) * NEG);
            float sv, cv; sincosf(fy * dv, &sv, &cv);
            s += vpW[dd*128 + 64 + 2*i] * sv + vpW[dd*128 + 64 + 2*i + 1] * cv;
        }
        ws[WS_PY + idx] = s;
        return;
    }
    idx -= 16384;
    if (idx < 16384) { ws[WS_WQT  + idx] = Wq [(idx & 127)*128 + (idx >> 7)]; return; }
    idx -= 16384;
    if (idx < 18432) {                         // SAWT[c][j]
        int c = idx / 144, j = idx % 144;
        ws[WS_SAWT + idx] = (j < 96) ? soW[j*128 + c] : awW[(j-96)*128 + c];
        return;
    }
    idx -= 18432;
    if (idx < 16384) { ws[WS_OPWT + idx] = opW[(idx & 127)*128 + (idx >> 7)]; return; }
    idx -= 16384;
    if (idx < 16384) { ws[WS_F1T  + idx] = f1W[(idx & 127)*128 + (idx >> 7)]; return; }
    idx -= 16384;
    if (idx < 16384) { ws[WS_F2T  + idx] = f2W[(idx & 127)*128 + (idx >> 7)]; return; }
    idx -= 16384;
    if (idx < 8192)  { ws[WS_WOT  + idx] = Wo [(idx & 63)*128 + (idx >> 6)]; return; }
    idx -= 8192;
    if (idx < 144)   { ws[WS_SAB  + idx] = (idx < 96) ? sob[idx] : awb[idx - 96]; }
}

// ============ value: v = W2T.bev + PX[x] + PY[y] + bias2  (K=256 GEMM tile) ============
__global__ __launch_bounds__(256) void value_k(const float* __restrict__ bev, float* __restrict__ ws)
{
    __shared__ __align__(16) float bt[256 * 32];   // [c][pos]
    int t = threadIdx.x, blk = blockIdx.x;
    int b = blk >> 9;                              // 512 tiles per batch
    int n0 = (blk & 511) << 5;
    const float* src = bev + (size_t)b * 256 * HWB + n0;
#pragma unroll
    for (int i = 0; i < 32; ++i) {
        int flat = i * 256 + t;
        bt[flat] = src[(size_t)(flat >> 5) * HWB + (flat & 31)];
    }
    __syncthreads();
    int p0 = (t >> 5) << 2, d0 = (t & 31) << 2;
    float4 a0 = {0,0,0,0}, a1 = a0, a2 = a0, a3 = a0;
    const float* WT = ws + WS_W2T;
    for (int c = 0; c < 256; ++c) {
        float4 xv = *(const float4*)&bt[c*32 + p0];
        float4 wv = *(const float4*)&WT[c*128 + d0];
        FMA4(a0, xv.x, wv); FMA4(a1, xv.y, wv); FMA4(a2, xv.z, wv); FMA4(a3, xv.w, wv);
    }
    const float* PX = ws + WS_PX; const float* PY = ws + WS_PY;
    float4 b2 = *(const float4*)&ws[WS_BIAS2 + d0];
    float* vout = ws + WS_V;
#define VSTORE(ACC, PI) { \
        int n = n0 + p0 + (PI); int x = n & 127, y = n >> 7; \
        float4 px = *(const float4*)&PX[x*128 + d0]; \
        float4 py = *(const float4*)&PY[y*128 + d0]; \
        ADD4(ACC, px); ADD4(ACC, py); ADD4(ACC, b2); \
        *(float4*)&vout[((size_t)b*HWB + n)*128 + d0] = ACC; }
    VSTORE(a0, 0) VSTORE(a1, 1) VSTORE(a2, 2) VSTORE(a3, 3)
#undef VSTORE
}

// ============ q = WqT.rv + bq, then sa = q @ SAWT + sab (fused, q-tile in LDS) ============
__global__ __launch_bounds__(256) void qsa_k(const float* __restrict__ rv, const float* __restrict__ bq,
                                             float* __restrict__ ws)
{
    __shared__ __align__(16) float sh[32 * 132];   // phase 1: [128][32] rv tile; phase 2: [32][132] q tile
    int t = threadIdx.x, blk = blockIdx.x;
    int b = blk >> 10;                             // 1024 tiles per batch
    int n0 = (blk & 1023) << 5;
    const float* src = rv + (size_t)b * 128 * 32768 + n0;
#pragma unroll
    for (int i = 0; i < 16; ++i) {
        int flat = i * 256 + t;
        sh[flat] = src[(size_t)(flat >> 5) * 32768 + (flat & 31)];
    }
    __syncthreads();
    int p0 = (t >> 5) << 2, d0 = (t & 31) << 2;
    float4 a0 = {0,0,0,0}, a1 = a0, a2 = a0, a3 = a0;
    const float* WT = ws + WS_WQT;
    for (int c = 0; c < 128; ++c) {
        float4 xv = *(const float4*)&sh[c*32 + p0];
        float4 wv = *(const float4*)&WT[c*128 + d0];
        FMA4(a0, xv.x, wv); FMA4(a1, xv.y, wv); FMA4(a2, xv.z, wv); FMA4(a3, xv.w, wv);
    }
    float4 bb = *(const float4*)&bq[d0];
    ADD4(a0, bb); ADD4(a1, bb); ADD4(a2, bb); ADD4(a3, bb);
    __syncthreads();                               // all reads of rv tile done
    float* qout = ws + WS_Q + ((size_t)b * 32768 + n0) * 128;
#define QST(ACC, PI) { \
        *(float4*)&qout[(size_t)(p0 + (PI))*128 + d0] = ACC; \
        *(float4*)&sh[(p0 + (PI))*132 + d0] = ACC; }
    QST(a0, 0) QST(a1, 1) QST(a2, 2) QST(a3, 3)
#undef QST
    __syncthreads();
    // ---- sa phase: 32 rows, 8 col-groups of float4 per thread (+1 masked) ----
    int r = t >> 3, j0 = t & 7;
    float4 s0 = {0,0,0,0}, s1 = s0, s2 = s0, s3 = s0, s4 = s0;
    const float* SW = ws + WS_SAWT;
    for (int c = 0; c < 128; ++c) {
        float xv = sh[r*132 + c];
        const float* wrow = SW + c*144;
        float4 w0 = *(const float4*)&wrow[4*j0];
        float4 w1 = *(const float4*)&wrow[4*j0 + 32];
        float4 w2 = *(const float4*)&wrow[4*j0 + 64];
        float4 w3 = *(const float4*)&wrow[4*j0 + 96];
        FMA4(s0, xv, w0); FMA4(s1, xv, w1); FMA4(s2, xv, w2); FMA4(s3, xv, w3);
        if (j0 < 4) {
            float4 w4 = *(const float4*)&wrow[128 + 4*j0];
            FMA4(s4, xv, w4);
        }
    }
    const float* sab = ws + WS_SAB;
    float* dst = ws + WS_SA + ((size_t)b * 32768 + n0 + r) * 144;
    float4 b0 = *(const float4*)&sab[4*j0];       ADD4(s0, b0); *(float4*)&dst[4*j0]       = s0;
    float4 b1 = *(const float4*)&sab[4*j0 + 32];  ADD4(s1, b1); *(float4*)&dst[4*j0 + 32]  = s1;
    float4 b2 = *(const float4*)&sab[4*j0 + 64];  ADD4(s2, b2); *(float4*)&dst[4*j0 + 64]  = s2;
    float4 b3 = *(const float4*)&sab[4*j0 + 96];  ADD4(s3, b3); *(float4*)&dst[4*j0 + 96]  = s3;
    if (j0 < 4) {
        float4 b4 = *(const float4*)&sab[128 + 4*j0]; ADD4(s4, b4); *(float4*)&dst[128 + 4*j0] = s4;
    }
}

// ============ sampling: softmax over P, bilinear gather, weighted sum ============
__global__ __launch_bounds__(256) void samp_k(const float* __restrict__ ref, float* __restrict__ ws)
{
    int t = threadIdx.x;
    int w = t >> 6, l = t & 63;
    int g = blockIdx.x * 4 + w;                    // query id, < 65536
    int b = g >> 15;
    const float* sa = ws + WS_SA + (size_t)g * 144;
    int hh = l >> 3, s = l & 7;
    float lg[6]; float mx = -1e30f;
#pragma unroll
    for (int p = 0; p < 6; ++p) { lg[p] = sa[96 + hh*6 + p]; mx = fmaxf(mx, lg[p]); }
    float ssum = 0.f;
#pragma unroll
    for (int p = 0; p < 6; ++p) { lg[p] = expf(lg[p] - mx); ssum += lg[p]; }
    float inv = 1.f / ssum;
    float rx = ref[(size_t)g*2], ry = ref[(size_t)g*2 + 1];
    const float* vb = ws + WS_V + ((size_t)b * HWB) * 128 + hh*16 + s*2;
    float a0 = 0.f, a1 = 0.f;
#pragma unroll
    for (int p = 0; p < 6; ++p) {
        float ox = sa[(hh*6 + p)*2], oy = sa[(hh*6 + p)*2 + 1];
        float xx = (rx + ox * 0.0078125f) * 128.f - 0.5f;   // (ref + off/W)*W - 0.5
        float yy = (ry + oy * 0.0078125f) * 128.f - 0.5f;
        float xf = floorf(xx), yf = floorf(yy);
        float lx = xx - xf, ly = yy - yf;
        int ix = (int)xf, iy = (int)yf;
        float c0 = 0.f, c1 = 0.f;
#define CORNER(XI, YI, WW) { int xi = (XI), yi = (YI); \
        if (xi >= 0 && xi < 128 && yi >= 0 && yi < 128) { \
            const float2 gv = *(const float2*)(vb + (size_t)(yi*128 + xi)*128); \
            float wv = (WW); c0 += wv * gv.x; c1 += wv * gv.y; } }
        CORNER(ix,     iy,     (1.f-lx)*(1.f-ly));
        CORNER(ix + 1, iy,     lx*(1.f-ly));
        CORNER(ix,     iy + 1, (1.f-lx)*ly);
        CORNER(ix + 1, iy + 1, lx*ly);
#undef CORNER
        float aw = lg[p] * inv;
        a0 += aw * c0; a1 += aw * c1;
    }
    float2 r2; r2.x = a0; r2.y = a1;
    *(float2*)(ws + WS_MS + (size_t)g*128 + hh*16 + s*2) = r2;
}

// ============ op proj + residual(q) + LN1 -> y1  (32 rows/block, 2 rows/thread) ============
__global__ __launch_bounds__(256) void opln_k(const float* __restrict__ opb,
    const float* __restrict__ ln1g, const float* __restrict__ ln1b, float* __restrict__ ws)
{
    __shared__ __align__(16) float xt[32 * 132];
    int t = threadIdx.x;
    size_t row0 = (size_t)blockIdx.x * 32;
    const float* src = ws + WS_MS + row0 * 128;
#pragma unroll
    for (int i = 0; i < 4; ++i) {
        int f4 = i * 256 + t; int r = f4 >> 5, c4 = f4 & 31;
        *(float4*)&xt[r*132 + c4*4] = *(const float4*)&src[r*128 + c4*4];
    }
    __syncthreads();
    int r0 = (t >> 4) << 1, j0 = (t & 15) << 2;
    const float* WT = ws + WS_OPWT;
    float4 A = {0,0,0,0}, Bv = A, C = A, Dv = A;
    for (int c = 0; c < 128; ++c) {
        float x0 = xt[r0*132 + c];
        float x1 = xt[r0*132 + 132 + c];
        float4 wa = *(const float4*)&WT[c*128 + j0];
        float4 wb = *(const float4*)&WT[c*128 + j0 + 64];
        FMA4(A, x0, wa); FMA4(Bv, x0, wb);
        FMA4(C, x1, wa); FMA4(Dv, x1, wb);
    }
    float4 oa = *(const float4*)&opb[j0], ob = *(const float4*)&opb[j0 + 64];
    float4 ga = *(const float4*)&ln1g[j0], gb = *(const float4*)&ln1g[j0 + 64];
    float4 la = *(const float4*)&ln1b[j0], lb = *(const float4*)&ln1b[j0 + 64];
#define LN1ROW(AA, BB, G) { \
    const float* qrow = ws + WS_Q + (size_t)(G) * 128; \
    float4 qa = *(const float4*)&qrow[j0], qb = *(const float4*)&qrow[j0 + 64]; \
    ADD4(AA, qa); ADD4(AA, oa); ADD4(BB, qb); ADD4(BB, ob); \
    float sm = AA.x + AA.y + AA.z + AA.w + BB.x + BB.y + BB.z + BB.w; \
    sm += __shfl_xor(sm, 1); sm += __shfl_xor(sm, 2); sm += __shfl_xor(sm, 4); sm += __shfl_xor(sm, 8); \
    float mean = sm * 0.0078125f; \
    AA.x -= mean; AA.y -= mean; AA.z -= mean; AA.w -= mean; \
    BB.x -= mean; BB.y -= mean; BB.z -= mean; BB.w -= mean; \
    float vv = AA.x*AA.x + AA.y*AA.y + AA.z*AA.z + AA.w*AA.w + BB.x*BB.x + BB.y*BB.y + BB.z*BB.z + BB.w*BB.w; \
    vv += __shfl_xor(vv, 1); vv += __shfl_xor(vv, 2); vv += __shfl_xor(vv, 4); vv += __shfl_xor(vv, 8); \
    float rstd = rsqrtf(vv * 0.0078125f + 1e-5f); \
    float4 ra, rb; \
    ra.x = AA.x*rstd*ga.x + la.x;  ra.y = AA.y*rstd*ga.y + la.y; \
    ra.z = AA.z*rstd*ga.z + la.z;  ra.w = AA.w*rstd*ga.w + la.w; \
    rb.x = BB.x*rstd*gb.x + lb.x; rb.y = BB.y*rstd*gb.y + lb.y; \
    rb.z = BB.z*rstd*gb.z + lb.z; rb.w = BB.w*rstd*gb.w + lb.w; \
    float* dstp = ws + WS_Y1 + (size_t)(G) * 128; \
    *(float4*)&dstp[j0] = ra; *(float4*)&dstp[j0 + 64] = rb; }
    LN1ROW(A, Bv, row0 + r0)
    LN1ROW(C, Dv, row0 + r0 + 1)
#undef LN1ROW
}

// ============ FFN hidden: t = gelu(y1 @ f1T + f1b)  (32 rows/block, 2 rows/thread) ============
__global__ __launch_bounds__(256) void f1_k(const float* __restrict__ f1b, float* __restrict__ ws)
{
    __shared__ __align__(16) float xt[32 * 132];
    int t = threadIdx.x;
    size_t row0 = (size_t)blockIdx.x * 32;
    const float* src = ws + WS_Y1 + row0 * 128;
#pragma unroll
    for (int i = 0; i < 4; ++i) {
        int f4 = i * 256 + t; int r = f4 >> 5, c4 = f4 & 31;
        *(float4*)&xt[r*132 + c4*4] = *(const float4*)&src[r*128 + c4*4];
    }
    __syncthreads();
    int r0 = (t >> 4) << 1, j0 = (t & 15) << 2;
    const float* WT = ws + WS_F1T;
    float4 A = {0,0,0,0}, Bv = A, C = A, Dv = A;
    for (int c = 0; c < 128; ++c) {
        float x0 = xt[r0*132 + c];
        float x1 = xt[r0*132 + 132 + c];
        float4 wa = *(const float4*)&WT[c*128 + j0];
        float4 wb = *(const float4*)&WT[c*128 + j0 + 64];
        FMA4(A, x0, wa); FMA4(Bv, x0, wb);
        FMA4(C, x1, wa); FMA4(Dv, x1, wb);
    }
    float4 ba = *(const float4*)&f1b[j0], bb = *(const float4*)&f1b[j0 + 64];
    ADD4(A, ba); ADD4(Bv, bb); ADD4(C, ba); ADD4(Dv, bb);
#define GELU(X) ((X) = 0.5f*(X)*(1.f + erff((X)*0.70710678118654752f)))
    GELU(A.x); GELU(A.y); GELU(A.z); GELU(A.w);
    GELU(Bv.x); GELU(Bv.y); GELU(Bv.z); GELU(Bv.w);
    GELU(C.x); GELU(C.y); GELU(C.z); GELU(C.w);
    GELU(Dv.x); GELU(Dv.y); GELU(Dv.z); GELU(Dv.w);
#undef GELU
    float* dst0 = ws + WS_T + (row0 + r0) * 128;
    *(float4*)&dst0[j0] = A; *(float4*)&dst0[j0 + 64] = Bv;
    float* dst1 = dst0 + 128;
    *(float4*)&dst1[j0] = C; *(float4*)&dst1[j0 + 64] = Dv;
}

// ============ z = t @ f2T + f2b + y1 ; LN2 ; out = yf @ WoT + bo (fused) ============
__global__ __launch_bounds__(256) void f2lnout_k(const float* __restrict__ f2b,
    const float* __restrict__ ln2g, const float* __restrict__ ln2b,
    const float* __restrict__ bo, float* __restrict__ out, float* __restrict__ ws)
{
    __shared__ __align__(16) float xt[16 * 132];
    int t = threadIdx.x;
    size_t row0 = (size_t)blockIdx.x * 16;
    const float* src = ws + WS_T + row0 * 128;
#pragma unroll
    for (int i = 0; i < 2; ++i) {
        int f4 = i * 256 + t; int r = f4 >> 5, c4 = f4 & 31;
        *(float4*)&xt[r*132 + c4*4] = *(const float4*)&src[r*128 + c4*4];
    }
    __syncthreads();
    int r = t >> 4, j0 = (t & 15) << 2;
    const float* WT = ws + WS_F2T;
    float4 A = {0,0,0,0}, Bv = {0,0,0,0};
    for (int c = 0; c < 128; ++c) {
        float xv = xt[r*132 + c];
        float4 wa = *(const float4*)&WT[c*128 + j0];
        float4 wb = *(const float4*)&WT[c*128 + j0 + 64];
        FMA4(A, xv, wa); FMA4(Bv, xv, wb);
    }
    size_t g = row0 + r;
    const float* yr = ws + WS_Y1 + g * 128;
    float4 ya = *(const float4*)&yr[j0], yb = *(const float4*)&yr[j0 + 64];
    float4 ba = *(const float4*)&f2b[j0], bb = *(const float4*)&f2b[j0 + 64];
    ADD4(A, ya); ADD4(A, ba); ADD4(Bv, yb); ADD4(Bv, bb);
    float sm = A.x + A.y + A.z + A.w + Bv.x + Bv.y + Bv.z + Bv.w;
    sm += __shfl_xor(sm, 1); sm += __shfl_xor(sm, 2); sm += __shfl_xor(sm, 4); sm += __shfl_xor(sm, 8);
    float mean = sm * 0.0078125f;
    A.x -= mean; A.y -= mean; A.z -= mean; A.w -= mean;
    Bv.x -= mean; Bv.y -= mean; Bv.z -= mean; Bv.w -= mean;
    float vv = A.x*A.x + A.y*A.y + A.z*A.z + A.w*A.w + Bv.x*Bv.x + Bv.y*Bv.y + Bv.z*Bv.z + Bv.w*Bv.w;
    vv += __shfl_xor(vv, 1); vv += __shfl_xor(vv, 2); vv += __shfl_xor(vv, 4); vv += __shfl_xor(vv, 8);
    float rstd = rsqrtf(vv * 0.0078125f + 1e-5f);
    float4 ga = *(const float4*)&ln2g[j0], gb = *(const float4*)&ln2g[j0 + 64];
    float4 la = *(const float4*)&ln2b[j0], lb = *(const float4*)&ln2b[j0 + 64];
    float4 ra, rb;
    ra.x = A.x*rstd*ga.x + la.x;  ra.y = A.y*rstd*ga.y + la.y;
    ra.z = A.z*rstd*ga.z + la.z;  ra.w = A.w*rstd*ga.w + la.w;
    rb.x = Bv.x*rstd*gb.x + lb.x; rb.y = Bv.y*rstd*gb.y + lb.y;
    rb.z = Bv.z*rstd*gb.z + lb.z; rb.w = Bv.w*rstd*gb.w + lb.w;
    // ---- reuse xt for the yf tile, then final projection ----
    __syncthreads();                               // all f2 reads of xt done
    *(float4*)&xt[r*132 + j0] = ra;
    *(float4*)&xt[r*132 + j0 + 64] = rb;
    __syncthreads();
    float4 O = {0,0,0,0};
    const float* WO = ws + WS_WOT;
    for (int c = 0; c < 128; ++c) {
        float xv = xt[r*132 + c];
        float4 wo = *(const float4*)&WO[c*64 + j0];
        FMA4(O, xv, wo);
    }
    float4 bba = *(const float4*)&bo[j0];
    ADD4(O, bba);
    *(float4*)&out[g*64 + j0] = O;
}

extern "C" void kernel_launch(void* const* d_in, const int* in_sizes, int n_in,
                              void* d_out, int out_size, void* d_ws, size_t ws_size,
                              hipStream_t stream) {
    const float* rv   = (const float*)d_in[0];
    const float* bev  = (const float*)d_in[1];
    const float* ref  = (const float*)d_in[2];
    const float* Wq   = (const float*)d_in[3];
    const float* bq   = (const float*)d_in[4];
    const float* Wv   = (const float*)d_in[5];
    const float* bv   = (const float*)d_in[6];
    const float* soW  = (const float*)d_in[7];
    const float* sob  = (const float*)d_in[8];
    const float* awW  = (const float*)d_in[9];
    const float* awb  = (const float*)d_in[10];
    const float* vpW  = (const float*)d_in[11];
    const float* vpb  = (const float*)d_in[12];
    const float* opW  = (const float*)d_in[13];
    const float* opb  = (const float*)d_in[14];
    const float* ln1g = (const float*)d_in[15];
    const float* ln1b = (const float*)d_in[16];
    const float* f1W  = (const float*)d_in[17];
    const float* f1b  = (const float*)d_in[18];
    const float* f2W  = (const float*)d_in[19];
    const float* f2b  = (const float*)d_in[20];
    const float* ln2g = (const float*)d_in[21];
    const float* ln2b = (const float*)d_in[22];
    const float* Wo   = (const float*)d_in[23];
    const float* bo   = (const float*)d_in[24];
    float* ws  = (float*)d_ws;
    float* out = (float*)d_out;

    prep_k   <<<618,   256, 0, stream>>>(vpW, Wv, bv, vpb, Wq, soW, awW, opW, f1W, f2W, Wo, sob, awb, ws);
    value_k  <<<1024,  256, 0, stream>>>(bev, ws);
    qsa_k    <<<2048,  256, 0, stream>>>(rv, bq, ws);
    samp_k   <<<16384, 256, 0, stream>>>(ref, ws);
    opln_k   <<<2048,  256, 0, stream>>>(opb, ln1g, ln1b, ws);
    f1_k     <<<2048,  256, 0, stream>>>(f1b, ws);
    f2lnout_k<<<4096,  256, 0, stream>>>(f2b, ln2g, ln2b, bo, out, ws);
}

// Round 6
// 700.092 us; speedup vs baseline: 1.2547x; 1.1060x over previous
//
#include <hip/hip_runtime.h>
#include <cmath>

// ---- problem constants ----
// B=2, d=128, C_bev=256, C_rv=64, Hrv=32, Wrv=1024 (Nq=32768), Hb=Wb=128 (HW=16384)
// heads=8, points=6, hd=16
#define HWB   16384
#define NQTOT 65536      // B * Nq

// ---- workspace layout (float offsets) ----
#define WS_W2T   0UL        // [256][128]  (vp_W @ Wv)^T  c-major
#define WS_BIAS2 32768UL    // [128]       vp_W@bv + vp_b
#define WS_PX    32896UL    // [128][128]  x-major: PX[x][dout]
#define WS_PY    49280UL    // [128][128]
#define WS_WQ2   65664UL    // [128][272]  [Wq^T | Wq^T@SAWT]  c-major
#define WS_OPWT  100480UL   // [128][128]
#define WS_F1T   116864UL
#define WS_F2T   133248UL
#define WS_WOT   149632UL   // [128][64]
#define WS_B3    157824UL   // [272]  [bq | bq@SAWT + sab]
#define WS_Q     158096UL   // [65536][128]   q (live until opln residual)
#define WS_V     8546704UL  // [2*16384][128]
#define WS_SA    12741008UL // [65536][144]   sa ; later region reused as y1
#define WS_Y1    12741008UL // [65536][128]
#define WS_MS    22178192UL // [65536][128]   msda out ; later FFN hidden t
#define WS_T     22178192UL
// total = 30,566,800 floats = 122.27 MB

#define FMA4(A, S, W) { A.x += (S)*(W).x; A.y += (S)*(W).y; A.z += (S)*(W).z; A.w += (S)*(W).w; }
#define ADD4(A, B4)   { A.x += (B4).x;    A.y += (B4).y;    A.z += (B4).z;    A.w += (B4).w;    }

// ============ prep: fused/transposed weight tables ============
__global__ __launch_bounds__(256) void prep_k(
    const float* __restrict__ vpW, const float* __restrict__ Wv,
    const float* __restrict__ bv,  const float* __restrict__ vpb,
    const float* __restrict__ Wq,  const float* __restrict__ soW,
    const float* __restrict__ awW, const float* __restrict__ opW,
    const float* __restrict__ f1W, const float* __restrict__ f2W,
    const float* __restrict__ Wo,  const float* __restrict__ sob,
    const float* __restrict__ awb, const float* __restrict__ bq,
    float* __restrict__ ws)
{
    int idx = blockIdx.x * 256 + threadIdx.x;
    const float NEG = -0.14391156831212787f;   // -ln(10000)/64
    if (idx < 32768) {                         // W2T[c][dout] = sum_k vpW[dout,k]*Wv[k,c]
        int c = idx >> 7, dd = idx & 127;
        float s = 0.f;
        for (int k = 0; k < 128; ++k) s += vpW[dd*128 + k] * Wv[k*256 + c];
        ws[WS_W2T + idx] = s;
        return;
    }
    idx -= 32768;
    if (idx < 128) {                           // bias2 = vpW@bv + vpb
        float s = vpb[idx];
        for (int k = 0; k < 128; ++k) s += vpW[idx*128 + k] * bv[k];
        ws[WS_BIAS2 + idx] = s;
        return;
    }
    idx -= 128;
    if (idx < 16384) {                         // PX[x][dout]
        int x = idx >> 7, dd = idx & 127;
        float fx = (float)x, s = 0.f;
        for (int i = 0; i < 32; ++i) {
            float dv = expf((float)(2*i) * NEG);
            float sv, cv; sincosf(fx * dv, &sv, &cv);
            s += vpW[dd*128 + 2*i] * sv + vpW[dd*128 + 2*i + 1] * cv;
        }
        ws[WS_PX + idx] = s;
        return;
    }
    idx -= 16384;
    if (idx < 16384) {                         // PY[y][dout]
        int y = idx >> 7, dd = idx & 127;
        float fy = (float)y, s = 0.f;
        for (int i = 0; i < 32; ++i) {
            float dv = expf((float)(2*i) * NEG);
            float sv, cv; sincosf(fy * dv, &sv, &cv);
            s += vpW[dd*128 + 64 + 2*i] * sv + vpW[dd*128 + 64 + 2*i + 1] * cv;
        }
        ws[WS_PY + idx] = s;
        return;
    }
    idx -= 16384;
    if (idx < 16384) {                         // WQ2 q-part: [c][j] = Wq[j][c]
        int c = idx >> 7, j = idx & 127;
        ws[WS_WQ2 + (size_t)c*272 + j] = Wq[j*128 + c];
        return;
    }
    idx -= 16384;
    if (idx < 18432) {                         // WQ2 sa-part: [c][128+jj] = sum_k Wq[k][c]*soaw[jj][k]
        int c = idx / 144, jj = idx % 144;
        const float* r = (jj < 96) ? (soW + jj*128) : (awW + (jj-96)*128);
        float s = 0.f;
        for (int k = 0; k < 128; k += 4) {
            float4 r4 = *(const float4*)&r[k];
            s += Wq[k*128 + c]       * r4.x + Wq[(k+1)*128 + c] * r4.y
               + Wq[(k+2)*128 + c]   * r4.z + Wq[(k+3)*128 + c] * r4.w;
        }
        ws[WS_WQ2 + (size_t)c*272 + 128 + jj] = s;
        return;
    }
    idx -= 18432;
    if (idx < 16384) { ws[WS_OPWT + idx] = opW[(idx & 127)*128 + (idx >> 7)]; return; }
    idx -= 16384;
    if (idx < 16384) { ws[WS_F1T  + idx] = f1W[(idx & 127)*128 + (idx >> 7)]; return; }
    idx -= 16384;
    if (idx < 16384) { ws[WS_F2T  + idx] = f2W[(idx & 127)*128 + (idx >> 7)]; return; }
    idx -= 16384;
    if (idx < 8192)  { ws[WS_WOT  + idx] = Wo [(idx & 63)*128 + (idx >> 6)]; return; }
    idx -= 8192;
    if (idx < 272) {                           // B3 = [bq | bq@SAWT + sab]
        if (idx < 128) { ws[WS_B3 + idx] = bq[idx]; return; }
        int jj = idx - 128;
        const float* r = (jj < 96) ? (soW + jj*128) : (awW + (jj-96)*128);
        float s = (jj < 96) ? sob[jj] : awb[jj-96];
        for (int k = 0; k < 128; ++k) s += bq[k] * r[k];
        ws[WS_B3 + idx] = s;
    }
}

// ============ value: v = W2T.bev + PX[x] + PY[y] + bias2  (K=256 GEMM tile) ============
__global__ __launch_bounds__(256) void value_k(const float* __restrict__ bev, float* __restrict__ ws)
{
    __shared__ __align__(16) float bt[256 * 32];   // [c][pos]
    int t = threadIdx.x, blk = blockIdx.x;
    int b = blk >> 9;                              // 512 tiles per batch
    int n0 = (blk & 511) << 5;
    const float* src = bev + (size_t)b * 256 * HWB + n0;
#pragma unroll
    for (int i = 0; i < 32; ++i) {
        int flat = i * 256 + t;
        bt[flat] = src[(size_t)(flat >> 5) * HWB + (flat & 31)];
    }
    __syncthreads();
    int p0 = (t >> 5) << 2, d0 = (t & 31) << 2;
    float4 a0 = {0,0,0,0}, a1 = a0, a2 = a0, a3 = a0;
    const float* WT = ws + WS_W2T;
    for (int c = 0; c < 256; ++c) {
        float4 xv = *(const float4*)&bt[c*32 + p0];
        float4 wv = *(const float4*)&WT[c*128 + d0];
        FMA4(a0, xv.x, wv); FMA4(a1, xv.y, wv); FMA4(a2, xv.z, wv); FMA4(a3, xv.w, wv);
    }
    const float* PX = ws + WS_PX; const float* PY = ws + WS_PY;
    float4 b2 = *(const float4*)&ws[WS_BIAS2 + d0];
    float* vout = ws + WS_V;
#define VSTORE(ACC, PI) { \
        int n = n0 + p0 + (PI); int x = n & 127, y = n >> 7; \
        float4 px = *(const float4*)&PX[x*128 + d0]; \
        float4 py = *(const float4*)&PY[y*128 + d0]; \
        ADD4(ACC, px); ADD4(ACC, py); ADD4(ACC, b2); \
        *(float4*)&vout[((size_t)b*HWB + n)*128 + d0] = ACC; }
    VSTORE(a0, 0) VSTORE(a1, 1) VSTORE(a2, 2) VSTORE(a3, 3)
#undef VSTORE
}

// ============ q,sa = rv^T @ WQ2 + B3  (single-phase fused GEMM) ============
__global__ __launch_bounds__(256) void qsa_k(const float* __restrict__ rv, float* __restrict__ ws)
{
    __shared__ __align__(16) float sh[128 * 32];   // [c][pos]
    int t = threadIdx.x, blk = blockIdx.x;
    int b = blk >> 10;                             // 1024 tiles per batch
    int n0 = (blk & 1023) << 5;
    const float* src = rv + (size_t)b * 128 * 32768 + n0;
#pragma unroll
    for (int i = 0; i < 16; ++i) {
        int flat = i * 256 + t;
        sh[flat] = src[(size_t)(flat >> 5) * 32768 + (flat & 31)];
    }
    __syncthreads();
    int pr = t >> 5;                               // 0..7 -> positions pr*4..pr*4+3
    int jc = t & 31;                               // col group (float4)
    bool hasC = (jc < 4);
    const float* W = ws + WS_WQ2;
    float4 qa0 = {0,0,0,0}, qa1 = qa0, qa2 = qa0, qa3 = qa0;   // q cols 4jc
    float4 sb0 = qa0, sb1 = qa0, sb2 = qa0, sb3 = qa0;          // sa cols 4jc
    float4 sc0 = qa0, sc1 = qa0, sc2 = qa0, sc3 = qa0;          // sa cols 128+4jc (jc<4)
    for (int c = 0; c < 128; ++c) {
        float4 x = *(const float4*)&sh[c*32 + pr*4];
        const float* wr = W + (size_t)c*272;
        float4 wA = *(const float4*)&wr[4*jc];
        float4 wB = *(const float4*)&wr[128 + 4*jc];
        FMA4(qa0, x.x, wA); FMA4(qa1, x.y, wA); FMA4(qa2, x.z, wA); FMA4(qa3, x.w, wA);
        FMA4(sb0, x.x, wB); FMA4(sb1, x.y, wB); FMA4(sb2, x.z, wB); FMA4(sb3, x.w, wB);
        if (hasC) {
            float4 wC = *(const float4*)&wr[256 + 4*jc];
            FMA4(sc0, x.x, wC); FMA4(sc1, x.y, wC); FMA4(sc2, x.z, wC); FMA4(sc3, x.w, wC);
        }
    }
    const float* B3 = ws + WS_B3;
    float4 bA = *(const float4*)&B3[4*jc];
    float4 bB = *(const float4*)&B3[128 + 4*jc];
    size_t row = (size_t)b * 32768 + n0 + pr*4;
    float* qout  = ws + WS_Q  + row * 128 + 4*jc;
    float* saout = ws + WS_SA + row * 144 + 4*jc;
    ADD4(qa0, bA); *(float4*)&qout[0]     = qa0;
    ADD4(qa1, bA); *(float4*)&qout[128]   = qa1;
    ADD4(qa2, bA); *(float4*)&qout[256]   = qa2;
    ADD4(qa3, bA); *(float4*)&qout[384]   = qa3;
    ADD4(sb0, bB); *(float4*)&saout[0]    = sb0;
    ADD4(sb1, bB); *(float4*)&saout[144]  = sb1;
    ADD4(sb2, bB); *(float4*)&saout[288]  = sb2;
    ADD4(sb3, bB); *(float4*)&saout[432]  = sb3;
    if (hasC) {
        float4 bC = *(const float4*)&B3[256 + 4*jc];
        ADD4(sc0, bC); *(float4*)&saout[128]       = sc0;
        ADD4(sc1, bC); *(float4*)&saout[144 + 128] = sc1;
        ADD4(sc2, bC); *(float4*)&saout[288 + 128] = sc2;
        ADD4(sc3, bC); *(float4*)&saout[432 + 128] = sc3;
    }
}

// ============ sampling: softmax over P, bilinear gather, weighted sum ============
__global__ __launch_bounds__(256) void samp_k(const float* __restrict__ ref, float* __restrict__ ws)
{
    int t = threadIdx.x;
    int w = t >> 6, l = t & 63;
    int g = blockIdx.x * 4 + w;                    // query id, < 65536
    int b = g >> 15;
    const float* sa = ws + WS_SA + (size_t)g * 144;
    int hh = l >> 3, s = l & 7;
    float lg[6]; float mx = -1e30f;
#pragma unroll
    for (int p = 0; p < 6; ++p) { lg[p] = sa[96 + hh*6 + p]; mx = fmaxf(mx, lg[p]); }
    float ssum = 0.f;
#pragma unroll
    for (int p = 0; p < 6; ++p) { lg[p] = expf(lg[p] - mx); ssum += lg[p]; }
    float inv = 1.f / ssum;
    float rx = ref[(size_t)g*2], ry = ref[(size_t)g*2 + 1];
    const float* vb = ws + WS_V + ((size_t)b * HWB) * 128 + hh*16 + s*2;
    float a0 = 0.f, a1 = 0.f;
#pragma unroll
    for (int p = 0; p < 6; ++p) {
        float ox = sa[(hh*6 + p)*2], oy = sa[(hh*6 + p)*2 + 1];
        float xx = (rx + ox * 0.0078125f) * 128.f - 0.5f;   // (ref + off/W)*W - 0.5
        float yy = (ry + oy * 0.0078125f) * 128.f - 0.5f;
        float xf = floorf(xx), yf = floorf(yy);
        float lx = xx - xf, ly = yy - yf;
        int ix = (int)xf, iy = (int)yf;
        float c0 = 0.f, c1 = 0.f;
#define CORNER(XI, YI, WW) { int xi = (XI), yi = (YI); \
        if (xi >= 0 && xi < 128 && yi >= 0 && yi < 128) { \
            const float2 gv = *(const float2*)(vb + (size_t)(yi*128 + xi)*128); \
            float wv = (WW); c0 += wv * gv.x; c1 += wv * gv.y; } }
        CORNER(ix,     iy,     (1.f-lx)*(1.f-ly));
        CORNER(ix + 1, iy,     lx*(1.f-ly));
        CORNER(ix,     iy + 1, (1.f-lx)*ly);
        CORNER(ix + 1, iy + 1, lx*ly);
#undef CORNER
        float aw = lg[p] * inv;
        a0 += aw * c0; a1 += aw * c1;
    }
    float2 r2; r2.x = a0; r2.y = a1;
    *(float2*)(ws + WS_MS + (size_t)g*128 + hh*16 + s*2) = r2;
}

// ============ op proj + residual(q) + LN1 -> y1  (32 rows/block, 2 rows/thread) ============
__global__ __launch_bounds__(256) void opln_k(const float* __restrict__ opb,
    const float* __restrict__ ln1g, const float* __restrict__ ln1b, float* __restrict__ ws)
{
    __shared__ __align__(16) float xt[32 * 132];
    int t = threadIdx.x;
    size_t row0 = (size_t)blockIdx.x * 32;
    const float* src = ws + WS_MS + row0 * 128;
#pragma unroll
    for (int i = 0; i < 4; ++i) {
        int f4 = i * 256 + t; int r = f4 >> 5, c4 = f4 & 31;
        *(float4*)&xt[r*132 + c4*4] = *(const float4*)&src[r*128 + c4*4];
    }
    __syncthreads();
    int r0 = (t >> 4) << 1, j0 = (t & 15) << 2;
    const float* WT = ws + WS_OPWT;
    float4 A = {0,0,0,0}, Bv = A, C = A, Dv = A;
    for (int c = 0; c < 128; ++c) {
        float x0 = xt[r0*132 + c];
        float x1 = xt[r0*132 + 132 + c];
        float4 wa = *(const float4*)&WT[c*128 + j0];
        float4 wb = *(const float4*)&WT[c*128 + j0 + 64];
        FMA4(A, x0, wa); FMA4(Bv, x0, wb);
        FMA4(C, x1, wa); FMA4(Dv, x1, wb);
    }
    float4 oa = *(const float4*)&opb[j0], ob = *(const float4*)&opb[j0 + 64];
    float4 ga = *(const float4*)&ln1g[j0], gb = *(const float4*)&ln1g[j0 + 64];
    float4 la = *(const float4*)&ln1b[j0], lb = *(const float4*)&ln1b[j0 + 64];
#define LN1ROW(AA, BB, G) { \
    const float* qrow = ws + WS_Q + (size_t)(G) * 128; \
    float4 qa = *(const float4*)&qrow[j0], qb = *(const float4*)&qrow[j0 + 64]; \
    ADD4(AA, qa); ADD4(AA, oa); ADD4(BB, qb); ADD4(BB, ob); \
    float sm = AA.x + AA.y + AA.z + AA.w + BB.x + BB.y + BB.z + BB.w; \
    sm += __shfl_xor(sm, 1); sm += __shfl_xor(sm, 2); sm += __shfl_xor(sm, 4); sm += __shfl_xor(sm, 8); \
    float mean = sm * 0.0078125f; \
    AA.x -= mean; AA.y -= mean; AA.z -= mean; AA.w -= mean; \
    BB.x -= mean; BB.y -= mean; BB.z -= mean; BB.w -= mean; \
    float vv = AA.x*AA.x + AA.y*AA.y + AA.z*AA.z + AA.w*AA.w + BB.x*BB.x + BB.y*BB.y + BB.z*BB.z + BB.w*BB.w; \
    vv += __shfl_xor(vv, 1); vv += __shfl_xor(vv, 2); vv += __shfl_xor(vv, 4); vv += __shfl_xor(vv, 8); \
    float rstd = rsqrtf(vv * 0.0078125f + 1e-5f); \
    float4 ra, rb; \
    ra.x = AA.x*rstd*ga.x + la.x;  ra.y = AA.y*rstd*ga.y + la.y; \
    ra.z = AA.z*rstd*ga.z + la.z;  ra.w = AA.w*rstd*ga.w + la.w; \
    rb.x = BB.x*rstd*gb.x + lb.x; rb.y = BB.y*rstd*gb.y + lb.y; \
    rb.z = BB.z*rstd*gb.z + lb.z; rb.w = BB.w*rstd*gb.w + lb.w; \
    float* dstp = ws + WS_Y1 + (size_t)(G) * 128; \
    *(float4*)&dstp[j0] = ra; *(float4*)&dstp[j0 + 64] = rb; }
    LN1ROW(A, Bv, row0 + r0)
    LN1ROW(C, Dv, row0 + r0 + 1)
#undef LN1ROW
}

// ============ FFN hidden: t = gelu(y1 @ f1T + f1b)  (32 rows/block, 2 rows/thread) ============
__global__ __launch_bounds__(256) void f1_k(const float* __restrict__ f1b, float* __restrict__ ws)
{
    __shared__ __align__(16) float xt[32 * 132];
    int t = threadIdx.x;
    size_t row0 = (size_t)blockIdx.x * 32;
    const float* src = ws + WS_Y1 + row0 * 128;
#pragma unroll
    for (int i = 0; i < 4; ++i) {
        int f4 = i * 256 + t; int r = f4 >> 5, c4 = f4 & 31;
        *(float4*)&xt[r*132 + c4*4] = *(const float4*)&src[r*128 + c4*4];
    }
    __syncthreads();
    int r0 = (t >> 4) << 1, j0 = (t & 15) << 2;
    const float* WT = ws + WS_F1T;
    float4 A = {0,0,0,0}, Bv = A, C = A, Dv = A;
    for (int c = 0; c < 128; ++c) {
        float x0 = xt[r0*132 + c];
        float x1 = xt[r0*132 + 132 + c];
        float4 wa = *(const float4*)&WT[c*128 + j0];
        float4 wb = *(const float4*)&WT[c*128 + j0 + 64];
        FMA4(A, x0, wa); FMA4(Bv, x0, wb);
        FMA4(C, x1, wa); FMA4(Dv, x1, wb);
    }
    float4 ba = *(const float4*)&f1b[j0], bb = *(const float4*)&f1b[j0 + 64];
    ADD4(A, ba); ADD4(Bv, bb); ADD4(C, ba); ADD4(Dv, bb);
#define GELU(X) ((X) = 0.5f*(X)*(1.f + erff((X)*0.70710678118654752f)))
    GELU(A.x); GELU(A.y); GELU(A.z); GELU(A.w);
    GELU(Bv.x); GELU(Bv.y); GELU(Bv.z); GELU(Bv.w);
    GELU(C.x); GELU(C.y); GELU(C.z); GELU(C.w);
    GELU(Dv.x); GELU(Dv.y); GELU(Dv.z); GELU(Dv.w);
#undef GELU
    float* dst0 = ws + WS_T + (row0 + r0) * 128;
    *(float4*)&dst0[j0] = A; *(float4*)&dst0[j0 + 64] = Bv;
    float* dst1 = dst0 + 128;
    *(float4*)&dst1[j0] = C; *(float4*)&dst1[j0 + 64] = Dv;
}

// ============ z = t @ f2T + f2b + y1 ; LN2 ; out = yf @ WoT + bo (fused) ============
__global__ __launch_bounds__(256) void f2lnout_k(const float* __restrict__ f2b,
    const float* __restrict__ ln2g, const float* __restrict__ ln2b,
    const float* __restrict__ bo, float* __restrict__ out, float* __restrict__ ws)
{
    __shared__ __align__(16) float xt[16 * 132];
    int t = threadIdx.x;
    size_t row0 = (size_t)blockIdx.x * 16;
    const float* src = ws + WS_T + row0 * 128;
#pragma unroll
    for (int i = 0; i < 2; ++i) {
        int f4 = i * 256 + t; int r = f4 >> 5, c4 = f4 & 31;
        *(float4*)&xt[r*132 + c4*4] = *(const float4*)&src[r*128 + c4*4];
    }
    __syncthreads();
    int r = t >> 4, j0 = (t & 15) << 2;
    const float* WT = ws + WS_F2T;
    float4 A = {0,0,0,0}, Bv = {0,0,0,0};
    for (int c = 0; c < 128; ++c) {
        float xv = xt[r*132 + c];
        float4 wa = *(const float4*)&WT[c*128 + j0];
        float4 wb = *(const float4*)&WT[c*128 + j0 + 64];
        FMA4(A, xv, wa); FMA4(Bv, xv, wb);
    }
    size_t g = row0 + r;
    const float* yr = ws + WS_Y1 + g * 128;
    float4 ya = *(const float4*)&yr[j0], yb = *(const float4*)&yr[j0 + 64];
    float4 ba = *(const float4*)&f2b[j0], bb = *(const float4*)&f2b[j0 + 64];
    ADD4(A, ya); ADD4(A, ba); ADD4(Bv, yb); ADD4(Bv, bb);
    float sm = A.x + A.y + A.z + A.w + Bv.x + Bv.y + Bv.z + Bv.w;
    sm += __shfl_xor(sm, 1); sm += __shfl_xor(sm, 2); sm += __shfl_xor(sm, 4); sm += __shfl_xor(sm, 8);
    float mean = sm * 0.0078125f;
    A.x -= mean; A.y -= mean; A.z -= mean; A.w -= mean;
    Bv.x -= mean; Bv.y -= mean; Bv.z -= mean; Bv.w -= mean;
    float vv = A.x*A.x + A.y*A.y + A.z*A.z + A.w*A.w + Bv.x*Bv.x + Bv.y*Bv.y + Bv.z*Bv.z + Bv.w*Bv.w;
    vv += __shfl_xor(vv, 1); vv += __shfl_xor(vv, 2); vv += __shfl_xor(vv, 4); vv += __shfl_xor(vv, 8);
    float rstd = rsqrtf(vv * 0.0078125f + 1e-5f);
    float4 ga = *(const float4*)&ln2g[j0], gb = *(const float4*)&ln2g[j0 + 64];
    float4 la = *(const float4*)&ln2b[j0], lb = *(const float4*)&ln2b[j0 + 64];
    float4 ra, rb;
    ra.x = A.x*rstd*ga.x + la.x;  ra.y = A.y*rstd*ga.y + la.y;
    ra.z = A.z*rstd*ga.z + la.z;  ra.w = A.w*rstd*ga.w + la.w;
    rb.x = Bv.x*rstd*gb.x + lb.x; rb.y = Bv.y*rstd*gb.y + lb.y;
    rb.z = Bv.z*rstd*gb.z + lb.z; rb.w = Bv.w*rstd*gb.w + lb.w;
    // ---- reuse xt for the yf tile, then final projection ----
    __syncthreads();                               // all f2 reads of xt done
    *(float4*)&xt[r*132 + j0] = ra;
    *(float4*)&xt[r*132 + j0 + 64] = rb;
    __syncthreads();
    float4 O = {0,0,0,0};
    const float* WO = ws + WS_WOT;
    for (int c = 0; c < 128; ++c) {
        float xv = xt[r*132 + c];
        float4 wo = *(const float4*)&WO[c*64 + j0];
        FMA4(O, xv, wo);
    }
    float4 bba = *(const float4*)&bo[j0];
    ADD4(O, bba);
    *(float4*)&out[g*64 + j0] = O;
}

extern "C" void kernel_launch(void* const* d_in, const int* in_sizes, int n_in,
                              void* d_out, int out_size, void* d_ws, size_t ws_size,
                              hipStream_t stream) {
    const float* rv   = (const float*)d_in[0];
    const float* bev  = (const float*)d_in[1];
    const float* ref  = (const float*)d_in[2];
    const float* Wq   = (const float*)d_in[3];
    const float* bq   = (const float*)d_in[4];
    const float* Wv   = (const float*)d_in[5];
    const float* bv   = (const float*)d_in[6];
    const float* soW  = (const float*)d_in[7];
    const float* sob  = (const float*)d_in[8];
    const float* awW  = (const float*)d_in[9];
    const float* awb  = (const float*)d_in[10];
    const float* vpW  = (const float*)d_in[11];
    const float* vpb  = (const float*)d_in[12];
    const float* opW  = (const float*)d_in[13];
    const float* opb  = (const float*)d_in[14];
    const float* ln1g = (const float*)d_in[15];
    const float* ln1b = (const float*)d_in[16];
    const float* f1W  = (const float*)d_in[17];
    const float* f1b  = (const float*)d_in[18];
    const float* f2W  = (const float*)d_in[19];
    const float* f2b  = (const float*)d_in[20];
    const float* ln2g = (const float*)d_in[21];
    const float* ln2b = (const float*)d_in[22];
    const float* Wo   = (const float*)d_in[23];
    const float* bo   = (const float*)d_in[24];
    float* ws  = (float*)d_ws;
    float* out = (float*)d_out;

    prep_k   <<<618,   256, 0, stream>>>(vpW, Wv, bv, vpb, Wq, soW, awW, opW, f1W, f2W, Wo, sob, awb, bq, ws);
    value_k  <<<1024,  256, 0, stream>>>(bev, ws);
    qsa_k    <<<2048,  256, 0, stream>>>(rv, ws);
    samp_k   <<<16384, 256, 0, stream>>>(ref, ws);
    opln_k   <<<2048,  256, 0, stream>>>(opb, ln1g, ln1b, ws);
    f1_k     <<<2048,  256, 0, stream>>>(f1b, ws);
    f2lnout_k<<<4096,  256, 0, stream>>>(f2b, ln2g, ln2b, bo, out, ws);
}

// Round 9
// 550.963 us; speedup vs baseline: 1.5944x; 1.2707x over previous
//
#include <hip/hip_runtime.h>
#include <cmath>

// ---- problem constants ----
// B=2, d=128, C_bev=256, C_rv=64, Hrv=32, Wrv=1024 (Nq=32768), Hb=Wb=128 (HW=16384)
// heads=8, points=6, hd=16
#define HWB   16384
#define NQTOT 65536      // B * Nq

// ---- workspace layout (float offsets) ----
#define WS_W2T   0UL        // [256][128]  (vp_W @ Wv)^T  c-major
#define WS_BIAS2 32768UL    // [128]       vp_W@bv + vp_b
#define WS_PX    32896UL    // [128][128]  x-major: PX[x][dout]
#define WS_PY    49280UL    // [128][128]
#define WS_WQ2   65664UL    // [128][272]  [Wq^T | Wq^T@SAWT]  c-major
#define WS_OPWT  100480UL   // [128][128]
#define WS_F1T   116864UL
#define WS_F2T   133248UL
#define WS_WOT   149632UL   // [128][64]
#define WS_B3    157824UL   // [272]  [bq | bq@SAWT + sab]
#define WS_Q     158096UL   // [65536][128]   q (live until opln residual)
#define WS_V     8546704UL  // [2*16384][128]
#define WS_SA    12741008UL // [65536][144]   sa ; later region reused as y1
#define WS_Y1    12741008UL // [65536][128]
#define WS_MS    22178192UL // [65536][128]   msda out ; later FFN hidden t
#define WS_T     22178192UL
// total = 30,566,800 floats = 122.27 MB

#define FMA4(A, S, W) { A.x += (S)*(W).x; A.y += (S)*(W).y; A.z += (S)*(W).z; A.w += (S)*(W).w; }
#define ADD4(A, B4)   { A.x += (B4).x;    A.y += (B4).y;    A.z += (B4).z;    A.w += (B4).w;    }

// stage 32 rows of a [*][128] row-major matrix into col-major xt[128][36]
// (coalesced float4 global reads; 16B-aligned float4 LDS reads in the GEMM loop)
#define STAGE_T32(SRC) { \
    _Pragma("unroll") \
    for (int i = 0; i < 4; ++i) { \
        int f4 = i * 256 + t; int r = f4 >> 5, c4 = (f4 & 31) << 2; \
        float4 v = *(const float4*)&(SRC)[(size_t)r * 128 + c4]; \
        xt[(c4+0)*36 + r] = v.x; xt[(c4+1)*36 + r] = v.y; \
        xt[(c4+2)*36 + r] = v.z; xt[(c4+3)*36 + r] = v.w; \
    } \
    __syncthreads(); }

// ============ prep: fused/transposed weight tables ============
__global__ __launch_bounds__(256) void prep_k(
    const float* __restrict__ vpW, const float* __restrict__ Wv,
    const float* __restrict__ bv,  const float* __restrict__ vpb,
    const float* __restrict__ Wq,  const float* __restrict__ soW,
    const float* __restrict__ awW, const float* __restrict__ opW,
    const float* __restrict__ f1W, const float* __restrict__ f2W,
    const float* __restrict__ Wo,  const float* __restrict__ sob,
    const float* __restrict__ awb, const float* __restrict__ bq,
    float* __restrict__ ws)
{
    int idx = blockIdx.x * 256 + threadIdx.x;
    const float NEG = -0.14391156831212787f;   // -ln(10000)/64
    if (idx < 32768) {                         // W2T[c][dout] = sum_k vpW[dout,k]*Wv[k,c]
        int c = idx >> 7, dd = idx & 127;
        float s = 0.f;
        for (int k = 0; k < 128; ++k) s += vpW[dd*128 + k] * Wv[k*256 + c];
        ws[WS_W2T + idx] = s;
        return;
    }
    idx -= 32768;
    if (idx < 128) {                           // bias2 = vpW@bv + vpb
        float s = vpb[idx];
        for (int k = 0; k < 128; ++k) s += vpW[idx*128 + k] * bv[k];
        ws[WS_BIAS2 + idx] = s;
        return;
    }
    idx -= 128;
    if (idx < 16384) {                         // PX[x][dout]
        int x = idx >> 7, dd = idx & 127;
        float fx = (float)x, s = 0.f;
        for (int i = 0; i < 32; ++i) {
            float dv = expf((float)(2*i) * NEG);
            float sv, cv; sincosf(fx * dv, &sv, &cv);
            s += vpW[dd*128 + 2*i] * sv + vpW[dd*128 + 2*i + 1] * cv;
        }
        ws[WS_PX + idx] = s;
        return;
    }
    idx -= 16384;
    if (idx < 16384) {                         // PY[y][dout]
        int y = idx >> 7, dd = idx & 127;
        float fy = (float)y, s = 0.f;
        for (int i = 0; i < 32; ++i) {
            float dv = expf((float)(2*i) * NEG);
            float sv, cv; sincosf(fy * dv, &sv, &cv);
            s += vpW[dd*128 + 64 + 2*i] * sv + vpW[dd*128 + 64 + 2*i + 1] * cv;
        }
        ws[WS_PY + idx] = s;
        return;
    }
    idx -= 16384;
    if (idx < 16384) {                         // WQ2 q-part: [c][j] = Wq[j][c]
        int c = idx >> 7, j = idx & 127;
        ws[WS_WQ2 + (size_t)c*272 + j] = Wq[j*128 + c];
        return;
    }
    idx -= 16384;
    if (idx < 18432) {                         // WQ2 sa-part: [c][128+jj] = sum_k Wq[k][c]*soaw[jj][k]
        int c = idx / 144, jj = idx % 144;
        const float* r = (jj < 96) ? (soW + jj*128) : (awW + (jj-96)*128);
        float s = 0.f;
        for (int k = 0; k < 128; k += 4) {
            float4 r4 = *(const float4*)&r[k];
            s += Wq[k*128 + c]       * r4.x + Wq[(k+1)*128 + c] * r4.y
               + Wq[(k+2)*128 + c]   * r4.z + Wq[(k+3)*128 + c] * r4.w;
        }
        ws[WS_WQ2 + (size_t)c*272 + 128 + jj] = s;
        return;
    }
    idx -= 18432;
    if (idx < 16384) { ws[WS_OPWT + idx] = opW[(idx & 127)*128 + (idx >> 7)]; return; }
    idx -= 16384;
    if (idx < 16384) { ws[WS_F1T  + idx] = f1W[(idx & 127)*128 + (idx >> 7)]; return; }
    idx -= 16384;
    if (idx < 16384) { ws[WS_F2T  + idx] = f2W[(idx & 127)*128 + (idx >> 7)]; return; }
    idx -= 16384;
    if (idx < 8192)  { ws[WS_WOT  + idx] = Wo [(idx & 63)*128 + (idx >> 6)]; return; }
    idx -= 8192;
    if (idx < 272) {                           // B3 = [bq | bq@SAWT + sab]
        if (idx < 128) { ws[WS_B3 + idx] = bq[idx]; return; }
        int jj = idx - 128;
        const float* r = (jj < 96) ? (soW + jj*128) : (awW + (jj-96)*128);
        float s = (jj < 96) ? sob[jj] : awb[jj-96];
        for (int k = 0; k < 128; ++k) s += bq[k] * r[k];
        ws[WS_B3 + idx] = s;
    }
}

// ============ value: v = W2T.bev + PX[x] + PY[y] + bias2  (K=256 GEMM tile) ============
__global__ __launch_bounds__(256) void value_k(const float* __restrict__ bev, float* __restrict__ ws)
{
    __shared__ __align__(16) float bt[256 * 32];   // [c][pos]
    int t = threadIdx.x, blk = blockIdx.x;
    int b = blk >> 9;                              // 512 tiles per batch
    int n0 = (blk & 511) << 5;
    const float* src = bev + (size_t)b * 256 * HWB + n0;
#pragma unroll
    for (int i = 0; i < 32; ++i) {
        int flat = i * 256 + t;
        bt[flat] = src[(size_t)(flat >> 5) * HWB + (flat & 31)];
    }
    __syncthreads();
    int p0 = (t >> 5) << 2, d0 = (t & 31) << 2;
    float4 a0 = {0,0,0,0}, a1 = a0, a2 = a0, a3 = a0;
    const float* WT = ws + WS_W2T;
    for (int c = 0; c < 256; ++c) {
        float4 xv = *(const float4*)&bt[c*32 + p0];
        float4 wv = *(const float4*)&WT[c*128 + d0];
        FMA4(a0, xv.x, wv); FMA4(a1, xv.y, wv); FMA4(a2, xv.z, wv); FMA4(a3, xv.w, wv);
    }
    const float* PX = ws + WS_PX; const float* PY = ws + WS_PY;
    float4 b2 = *(const float4*)&ws[WS_BIAS2 + d0];
    float* vout = ws + WS_V;
#define VSTORE(ACC, PI) { \
        int n = n0 + p0 + (PI); int x = n & 127, y = n >> 7; \
        float4 px = *(const float4*)&PX[x*128 + d0]; \
        float4 py = *(const float4*)&PY[y*128 + d0]; \
        ADD4(ACC, px); ADD4(ACC, py); ADD4(ACC, b2); \
        *(float4*)&vout[((size_t)b*HWB + n)*128 + d0] = ACC; }
    VSTORE(a0, 0) VSTORE(a1, 1) VSTORE(a2, 2) VSTORE(a3, 3)
#undef VSTORE
}

// ============ q,sa = rv^T @ WQ2 + B3  (single-phase fused GEMM) ============
__global__ __launch_bounds__(256) void qsa_k(const float* __restrict__ rv, float* __restrict__ ws)
{
    __shared__ __align__(16) float sh[128 * 32];   // [c][pos]
    int t = threadIdx.x, blk = blockIdx.x;
    int b = blk >> 10;                             // 1024 tiles per batch
    int n0 = (blk & 1023) << 5;
    const float* src = rv + (size_t)b * 128 * 32768 + n0;
#pragma unroll
    for (int i = 0; i < 16; ++i) {
        int flat = i * 256 + t;
        sh[flat] = src[(size_t)(flat >> 5) * 32768 + (flat & 31)];
    }
    __syncthreads();
    int pr = t >> 5;                               // 0..7 -> positions pr*4..pr*4+3
    int jc = t & 31;                               // col group (float4)
    bool hasC = (jc < 4);
    const float* W = ws + WS_WQ2;
    float4 qa0 = {0,0,0,0}, qa1 = qa0, qa2 = qa0, qa3 = qa0;   // q cols 4jc
    float4 sb0 = qa0, sb1 = qa0, sb2 = qa0, sb3 = qa0;          // sa cols 4jc
    float4 sc0 = qa0, sc1 = qa0, sc2 = qa0, sc3 = qa0;          // sa cols 128+4jc (jc<4)
    for (int c = 0; c < 128; ++c) {
        float4 x = *(const float4*)&sh[c*32 + pr*4];
        const float* wr = W + (size_t)c*272;
        float4 wA = *(const float4*)&wr[4*jc];
        float4 wB = *(const float4*)&wr[128 + 4*jc];
        FMA4(qa0, x.x, wA); FMA4(qa1, x.y, wA); FMA4(qa2, x.z, wA); FMA4(qa3, x.w, wA);
        FMA4(sb0, x.x, wB); FMA4(sb1, x.y, wB); FMA4(sb2, x.z, wB); FMA4(sb3, x.w, wB);
        if (hasC) {
            float4 wC = *(const float4*)&wr[256 + 4*jc];
            FMA4(sc0, x.x, wC); FMA4(sc1, x.y, wC); FMA4(sc2, x.z, wC); FMA4(sc3, x.w, wC);
        }
    }
    const float* B3 = ws + WS_B3;
    float4 bA = *(const float4*)&B3[4*jc];
    float4 bB = *(const float4*)&B3[128 + 4*jc];
    size_t row = (size_t)b * 32768 + n0 + pr*4;
    float* qout  = ws + WS_Q  + row * 128 + 4*jc;
    float* saout = ws + WS_SA + row * 144 + 4*jc;
    ADD4(qa0, bA); *(float4*)&qout[0]     = qa0;
    ADD4(qa1, bA); *(float4*)&qout[128]   = qa1;
    ADD4(qa2, bA); *(float4*)&qout[256]   = qa2;
    ADD4(qa3, bA); *(float4*)&qout[384]   = qa3;
    ADD4(sb0, bB); *(float4*)&saout[0]    = sb0;
    ADD4(sb1, bB); *(float4*)&saout[144]  = sb1;
    ADD4(sb2, bB); *(float4*)&saout[288]  = sb2;
    ADD4(sb3, bB); *(float4*)&saout[432]  = sb3;
    if (hasC) {
        float4 bC = *(const float4*)&B3[256 + 4*jc];
        ADD4(sc0, bC); *(float4*)&saout[128]       = sc0;
        ADD4(sc1, bC); *(float4*)&saout[144 + 128] = sc1;
        ADD4(sc2, bC); *(float4*)&saout[288 + 128] = sc2;
        ADD4(sc3, bC); *(float4*)&saout[432 + 128] = sc3;
    }
}

// ============ sampling: softmax over P, bilinear gather, weighted sum ============
__global__ __launch_bounds__(256) void samp_k(const float* __restrict__ ref, float* __restrict__ ws)
{
    int t = threadIdx.x;
    int w = t >> 6, l = t & 63;
    int g = blockIdx.x * 4 + w;                    // query id, < 65536
    int b = g >> 15;
    const float* sa = ws + WS_SA + (size_t)g * 144;
    int hh = l >> 3, s = l & 7;
    float lg[6]; float mx = -1e30f;
#pragma unroll
    for (int p = 0; p < 6; ++p) { lg[p] = sa[96 + hh*6 + p]; mx = fmaxf(mx, lg[p]); }
    float ssum = 0.f;
#pragma unroll
    for (int p = 0; p < 6; ++p) { lg[p] = expf(lg[p] - mx); ssum += lg[p]; }
    float inv = 1.f / ssum;
    float rx = ref[(size_t)g*2], ry = ref[(size_t)g*2 + 1];
    const float* vb = ws + WS_V + ((size_t)b * HWB) * 128 + hh*16 + s*2;
    float a0 = 0.f, a1 = 0.f;
#pragma unroll
    for (int p = 0; p < 6; ++p) {
        float ox = sa[(hh*6 + p)*2], oy = sa[(hh*6 + p)*2 + 1];
        float xx = (rx + ox * 0.0078125f) * 128.f - 0.5f;   // (ref + off/W)*W - 0.5
        float yy = (ry + oy * 0.0078125f) * 128.f - 0.5f;
        float xf = floorf(xx), yf = floorf(yy);
        float lx = xx - xf, ly = yy - yf;
        int ix = (int)xf, iy = (int)yf;
        float c0 = 0.f, c1 = 0.f;
#define CORNER(XI, YI, WW) { int xi = (XI), yi = (YI); \
        if (xi >= 0 && xi < 128 && yi >= 0 && yi < 128) { \
            const float2 gv = *(const float2*)(vb + (size_t)(yi*128 + xi)*128); \
            float wv = (WW); c0 += wv * gv.x; c1 += wv * gv.y; } }
        CORNER(ix,     iy,     (1.f-lx)*(1.f-ly));
        CORNER(ix + 1, iy,     lx*(1.f-ly));
        CORNER(ix,     iy + 1, (1.f-lx)*ly);
        CORNER(ix + 1, iy + 1, lx*ly);
#undef CORNER
        float aw = lg[p] * inv;
        a0 += aw * c0; a1 += aw * c1;
    }
    float2 r2; r2.x = a0; r2.y = a1;
    *(float2*)(ws + WS_MS + (size_t)g*128 + hh*16 + s*2) = r2;
}

// ============ op proj + residual(q) + LN1 -> y1  (32 rows, 4x4 per thread) ============
__global__ __launch_bounds__(256) void opln_k(const float* __restrict__ opb,
    const float* __restrict__ ln1g, const float* __restrict__ ln1b, float* __restrict__ ws)
{
    __shared__ __align__(16) float xt[128 * 36];
    int t = threadIdx.x;
    size_t row0 = (size_t)blockIdx.x * 32;
    const float* src = ws + WS_MS + row0 * 128;
    STAGE_T32(src)
    int d0 = (t & 31) << 2, rbase = (t >> 5) << 2;
    const float* WT = ws + WS_OPWT;
    float4 a0 = {0,0,0,0}, a1 = a0, a2 = a0, a3 = a0;
#pragma unroll 4
    for (int c = 0; c < 128; ++c) {
        float4 x = *(const float4*)&xt[c*36 + rbase];
        float4 w = *(const float4*)&WT[c*128 + d0];
        FMA4(a0, x.x, w); FMA4(a1, x.y, w); FMA4(a2, x.z, w); FMA4(a3, x.w, w);
    }
    float4 ob = *(const float4*)&opb[d0];
    float4 g4 = *(const float4*)&ln1g[d0];
    float4 b4 = *(const float4*)&ln1b[d0];
    float4 acc[4] = {a0, a1, a2, a3};
#pragma unroll
    for (int i = 0; i < 4; ++i) {
        size_t grow = row0 + rbase + i;
        float4 q4 = *(const float4*)&ws[WS_Q + grow*128 + d0];
        float4 A = acc[i];
        ADD4(A, q4); ADD4(A, ob);
        float sm = A.x + A.y + A.z + A.w;
        sm += __shfl_xor(sm,1); sm += __shfl_xor(sm,2); sm += __shfl_xor(sm,4);
        sm += __shfl_xor(sm,8); sm += __shfl_xor(sm,16);
        float mean = sm * 0.0078125f;
        A.x -= mean; A.y -= mean; A.z -= mean; A.w -= mean;
        float vv = A.x*A.x + A.y*A.y + A.z*A.z + A.w*A.w;
        vv += __shfl_xor(vv,1); vv += __shfl_xor(vv,2); vv += __shfl_xor(vv,4);
        vv += __shfl_xor(vv,8); vv += __shfl_xor(vv,16);
        float rstd = rsqrtf(vv * 0.0078125f + 1e-5f);
        float4 r4;
        r4.x = A.x*rstd*g4.x + b4.x; r4.y = A.y*rstd*g4.y + b4.y;
        r4.z = A.z*rstd*g4.z + b4.z; r4.w = A.w*rstd*g4.w + b4.w;
        *(float4*)&ws[WS_Y1 + grow*128 + d0] = r4;
    }
}

// ============ FFN hidden: t = gelu(y1 @ f1T + f1b)  (32 rows, 4x4 per thread) ============
__global__ __launch_bounds__(256) void f1_k(const float* __restrict__ f1b, float* __restrict__ ws)
{
    __shared__ __align__(16) float xt[128 * 36];
    int t = threadIdx.x;
    size_t row0 = (size_t)blockIdx.x * 32;
    const float* src = ws + WS_Y1 + row0 * 128;
    STAGE_T32(src)
    int d0 = (t & 31) << 2, rbase = (t >> 5) << 2;
    const float* WT = ws + WS_F1T;
    float4 a0 = {0,0,0,0}, a1 = a0, a2 = a0, a3 = a0;
#pragma unroll 4
    for (int c = 0; c < 128; ++c) {
        float4 x = *(const float4*)&xt[c*36 + rbase];
        float4 w = *(const float4*)&WT[c*128 + d0];
        FMA4(a0, x.x, w); FMA4(a1, x.y, w); FMA4(a2, x.z, w); FMA4(a3, x.w, w);
    }
    float4 bb = *(const float4*)&f1b[d0];
    float4 acc[4] = {a0, a1, a2, a3};
#pragma unroll
    for (int i = 0; i < 4; ++i) {
        float4 A = acc[i];
        ADD4(A, bb);
#define GELU(X) ((X) = 0.5f*(X)*(1.f + erff((X)*0.70710678118654752f)))
        GELU(A.x); GELU(A.y); GELU(A.z); GELU(A.w);
#undef GELU
        *(float4*)&ws[WS_T + (row0 + rbase + i)*128 + d0] = A;
    }
}

// ============ z = t @ f2T + f2b + y1 ; LN2 ; out = yf @ WoT + bo (fused, 32 rows) ============
__global__ __launch_bounds__(256) void f2lnout_k(const float* __restrict__ f2b,
    const float* __restrict__ ln2g, const float* __restrict__ ln2b,
    const float* __restrict__ bo, float* __restrict__ out, float* __restrict__ ws)
{
    __shared__ __align__(16) float xt[128 * 36];
    int t = threadIdx.x;
    size_t row0 = (size_t)blockIdx.x * 32;
    const float* src = ws + WS_T + row0 * 128;
    STAGE_T32(src)
    int d0 = (t & 31) << 2, rbase = (t >> 5) << 2;
    const float* WT = ws + WS_F2T;
    float4 a0 = {0,0,0,0}, a1 = a0, a2 = a0, a3 = a0;
#pragma unroll 4
    for (int c = 0; c < 128; ++c) {
        float4 x = *(const float4*)&xt[c*36 + rbase];
        float4 w = *(const float4*)&WT[c*128 + d0];
        FMA4(a0, x.x, w); FMA4(a1, x.y, w); FMA4(a2, x.z, w); FMA4(a3, x.w, w);
    }
    __syncthreads();                               // all f2 reads of xt done
    float4 fb = *(const float4*)&f2b[d0];
    float4 g4 = *(const float4*)&ln2g[d0];
    float4 b4 = *(const float4*)&ln2b[d0];
    float4 acc[4] = {a0, a1, a2, a3};
#pragma unroll
    for (int i = 0; i < 4; ++i) {
        size_t grow = row0 + rbase + i;
        float4 y4 = *(const float4*)&ws[WS_Y1 + grow*128 + d0];
        float4 A = acc[i];
        ADD4(A, y4); ADD4(A, fb);
        float sm = A.x + A.y + A.z + A.w;
        sm += __shfl_xor(sm,1); sm += __shfl_xor(sm,2); sm += __shfl_xor(sm,4);
        sm += __shfl_xor(sm,8); sm += __shfl_xor(sm,16);
        float mean = sm * 0.0078125f;
        A.x -= mean; A.y -= mean; A.z -= mean; A.w -= mean;
        float vv = A.x*A.x + A.y*A.y + A.z*A.z + A.w*A.w;
        vv += __shfl_xor(vv,1); vv += __shfl_xor(vv,2); vv += __shfl_xor(vv,4);
        vv += __shfl_xor(vv,8); vv += __shfl_xor(vv,16);
        float rstd = rsqrtf(vv * 0.0078125f + 1e-5f);
        int rloc = rbase + i;
        // write normalized yf transposed into xt: xt[col][row]
        xt[(d0+0)*36 + rloc] = A.x*rstd*g4.x + b4.x;
        xt[(d0+1)*36 + rloc] = A.y*rstd*g4.y + b4.y;
        xt[(d0+2)*36 + rloc] = A.z*rstd*g4.z + b4.z;
        xt[(d0+3)*36 + rloc] = A.w*rstd*g4.w + b4.w;
    }
    __syncthreads();
    // ---- out = yf @ WoT + bo : 2 rows x 4 cols per thread ----
    int rr = (t >> 4) << 1;                        // 0..30
    int j0 = (t & 15) << 2;                        // 0..60
    const float* WO = ws + WS_WOT;
    float4 O0 = {0,0,0,0}, O1 = O0;
#pragma unroll 4
    for (int c = 0; c < 128; ++c) {
        float x0 = xt[c*36 + rr];
        float x1 = xt[c*36 + rr + 1];
        float4 w = *(const float4*)&WO[c*64 + j0];
        FMA4(O0, x0, w); FMA4(O1, x1, w);
    }
    float4 bb = *(const float4*)&bo[j0];
    ADD4(O0, bb); ADD4(O1, bb);
    *(float4*)&out[(row0 + rr)*64 + j0]     = O0;
    *(float4*)&out[(row0 + rr + 1)*64 + j0] = O1;
}

extern "C" void kernel_launch(void* const* d_in, const int* in_sizes, int n_in,
                              void* d_out, int out_size, void* d_ws, size_t ws_size,
                              hipStream_t stream) {
    const float* rv   = (const float*)d_in[0];
    const float* bev  = (const float*)d_in[1];
    const float* ref  = (const float*)d_in[2];
    const float* Wq   = (const float*)d_in[3];
    const float* bq   = (const float*)d_in[4];
    const float* Wv   = (const float*)d_in[5];
    const float* bv   = (const float*)d_in[6];
    const float* soW  = (const float*)d_in[7];
    const float* sob  = (const float*)d_in[8];
    const float* awW  = (const float*)d_in[9];
    const float* awb  = (const float*)d_in[10];
    const float* vpW  = (const float*)d_in[11];
    const float* vpb  = (const float*)d_in[12];
    const float* opW  = (const float*)d_in[13];
    const float* opb  = (const float*)d_in[14];
    const float* ln1g = (const float*)d_in[15];
    const float* ln1b = (const float*)d_in[16];
    const float* f1W  = (const float*)d_in[17];
    const float* f1b  = (const float*)d_in[18];
    const float* f2W  = (const float*)d_in[19];
    const float* f2b  = (const float*)d_in[20];
    const float* ln2g = (const float*)d_in[21];
    const float* ln2b = (const float*)d_in[22];
    const float* Wo   = (const float*)d_in[23];
    const float* bo   = (const float*)d_in[24];
    float* ws  = (float*)d_ws;
    float* out = (float*)d_out;

    prep_k   <<<618,   256, 0, stream>>>(vpW, Wv, bv, vpb, Wq, soW, awW, opW, f1W, f2W, Wo, sob, awb, bq, ws);
    value_k  <<<1024,  256, 0, stream>>>(bev, ws);
    qsa_k    <<<2048,  256, 0, stream>>>(rv, ws);
    samp_k   <<<16384, 256, 0, stream>>>(ref, ws);
    opln_k   <<<2048,  256, 0, stream>>>(opb, ln1g, ln1b, ws);
    f1_k     <<<2048,  256, 0, stream>>>(f1b, ws);
    f2lnout_k<<<2048,  256, 0, stream>>>(f2b, ln2g, ln2b, bo, out, ws);
}